// Round 7
// baseline (582.400 us; speedup 1.0000x reference)
//
#include <hip/hip_runtime.h>
#include <math.h>

#define B_GRAPHS 50
#define NPG0     2000
#define EPG      12000
#define F_IN_C   256
#define NHID     128
#define N0       (B_GRAPHS * NPG0)   // 100000
#define NE       (B_GRAPHS * EPG)    // 600000
#define RSEG     32                  // readout segments per graph (latency-bound gather)
#define GSLOTS   7                   // ceil(50 graphs / 8 XCDs)
#define CPAD     136
#define KMAX     1600                // max next-layer nodes per graph (layer-0 k)

typedef _Float16 f16x8 __attribute__((ext_vector_type(8)));
typedef float    f32x4 __attribute__((ext_vector_type(4)));

static inline int cdiv(int a, int b) { return (a + b - 1) / b; }

// ---------------- startup fill: zero cnt (N0) + accum ----------------
__global__ void k_fill_start(int* __restrict__ cnt, float* __restrict__ accum) {
    int i = blockIdx.x * 256 + threadIdx.x;
    if (i < N0) cnt[i] = 0;
    if (i < B_GRAPHS * 256) accum[i] = 0.f;
}

// ------- edge init + degree count (cnt pre-zeroed) + all weight transposes -------
__global__ void k_init_cvt(const int* __restrict__ ei, int* __restrict__ esrc,
                           int* __restrict__ edst, float* __restrict__ ew,
                           int* __restrict__ cnt,
                           const float* __restrict__ W1, const float* __restrict__ W2,
                           const float* __restrict__ W3, _Float16* __restrict__ WT1,
                           _Float16* __restrict__ WT2, _Float16* __restrict__ WT3) {
    int t = blockIdx.x * 256 + threadIdx.x;
    if (t < NE) {
        int d = ei[NE + t];
        esrc[t] = ei[t]; edst[t] = d; ew[t] = 1.0f;
        atomicAdd(&cnt[d], 1);
    }
    if (t < 128 * 256) {
        int n = t >> 8, kk = t & 255;
        WT1[t] = (_Float16)W1[kk * 128 + n];
    } else if (t < 128 * 256 + 128 * 128) {
        int u = t - 32768; int n = u >> 7, kk = u & 127;
        WT2[u] = (_Float16)W2[kk * 128 + n];
    } else if (t < 128 * 256 + 2 * 128 * 128) {
        int u = t - 49152; int n = u >> 7, kk = u & 127;
        WT3[u] = (_Float16)W3[kk * 128 + n];
    }
}

// ============ FAT kernel: GEMM blocks + scancsr blocks (+ pool blocks) ============
// Blocks [0,NG): weight-stationary MFMA GEMM, 64-row M-tile (unchanged structure).
// Blocks [NG,NG+50): per-graph CSR build (scan + LDS-cursor edge fill) — data-
//   independent of the GEMM (reads only edges/cnt from topk of previous layer).
// Blocks [NG+50,...) when POOL: readout partials of PREVIOUS layer (reads X/perm/
//   gate only — same inputs the GEMM gathers; no write overlap with GEMM's H).
// All three roles only read buffers the others don't write -> safe in one launch.
template<int FP32IN, int F, int GATHER, int POOL>
__global__ __launch_bounds__(256) void k_fat(const void* __restrict__ Xin,
                                             const _Float16* __restrict__ WT,
                                             const int* __restrict__ perm,
                                             const float* __restrict__ gate,
                                             _Float16* __restrict__ H, int N,
                                             const int* __restrict__ cnt,
                                             int* __restrict__ offs,
                                             const int* __restrict__ esrc,
                                             const int* __restrict__ edst,
                                             const float* __restrict__ ew,
                                             int* __restrict__ csr_src,
                                             float* __restrict__ csr_norm,
                                             int npg, int NG,
                                             float* __restrict__ pmax,
                                             float* __restrict__ psum) {
    constexpr int KH  = (F > 128) ? 128 : F;      // K-cols staged per phase (=128)
    constexpr int K8H = KH / 8;
    constexpr int SMEMSZ = (128 * KH > 64 * CPAD) ? 128 * KH : 64 * CPAD;
    __shared__ _Float16 smem[SMEMSZ];             // 32 KB; scancsr overlays ints
    const int bid = blockIdx.x;
    const int tid = threadIdx.x;

    if (bid < NG) {
        // ---------------- GEMM role ----------------
        const int wave = tid >> 6, lane = tid & 63;
        const int quad = lane >> 4, l16 = lane & 15;
        const int m_blk = bid * 64;

        f32x4 acc[8];
#pragma unroll
        for (int j = 0; j < 8; ++j) acc[j] = {0.f, 0.f, 0.f, 0.f};

        int row0 = m_blk + wave * 16 + l16;
        if (row0 > N - 1) row0 = N - 1;
        _Float16 g0 = (_Float16)1.0f;
        if (GATHER) {
            g0 = (_Float16)gate[row0];
            row0 = perm[row0];
        }
        const int sx = l16 & 7;
        constexpr int NKQ = F / 32;

        if (FP32IN) {
            constexpr int PD = (NKQ < 4) ? NKQ : 4;
            const float* base0 = (const float*)Xin + (size_t)row0 * F + quad * 8;
            float4 p0[PD][2];
#pragma unroll
            for (int i = 0; i < PD; ++i) {
                p0[i][0] = ((const float4*)(base0 + i * 32))[0];
                p0[i][1] = ((const float4*)(base0 + i * 32))[1];
            }
#pragma unroll
            for (int c = tid; c < 128 * K8H; c += 256) {
                int n = c / K8H, k8 = c - n * K8H;
                f16x8 v = *(const f16x8*)&WT[(size_t)(n * (F / 8) + k8) * 8];
                *(f16x8*)&smem[n * KH + ((k8 ^ (n & 7)) << 3)] = v;
            }
            __syncthreads();
#pragma unroll
            for (int kq = 0; kq < NKQ; ++kq) {
                if (KH < F && kq == NKQ / 2) {
                    __syncthreads();
#pragma unroll
                    for (int c = tid; c < 128 * K8H; c += 256) {
                        int n = c / K8H, k8 = c - n * K8H;
                        f16x8 v = *(const f16x8*)&WT[(size_t)(n * (F / 8) + K8H + k8) * 8];
                        *(f16x8*)&smem[n * KH + ((k8 ^ (n & 7)) << 3)] = v;
                    }
                    __syncthreads();
                }
                const int b = kq % PD;
                float4 f0 = p0[b][0], f1 = p0[b][1];
                if (kq + PD < NKQ) {
                    p0[b][0] = ((const float4*)(base0 + (kq + PD) * 32))[0];
                    p0[b][1] = ((const float4*)(base0 + (kq + PD) * 32))[1];
                }
                f16x8 af0 = (f16x8){(_Float16)f0.x,(_Float16)f0.y,(_Float16)f0.z,(_Float16)f0.w,
                                    (_Float16)f1.x,(_Float16)f1.y,(_Float16)f1.z,(_Float16)f1.w};
                f16x8 bf[8];
#pragma unroll
                for (int j = 0; j < 8; ++j)
                    bf[j] = *(const f16x8*)&smem[(j * 16 + l16) * KH + (((((kq & 3) << 2) + quad) ^ sx) << 3)];
#pragma unroll
                for (int j = 0; j < 8; ++j)
                    acc[j] = __builtin_amdgcn_mfma_f32_16x16x32_f16(af0, bf[j], acc[j], 0, 0, 0);
            }
        } else {
#pragma unroll
            for (int c = tid; c < 128 * K8H; c += 256) {
                int n = c / K8H, k8 = c - n * K8H;
                f16x8 v = *(const f16x8*)&WT[(size_t)(n * K8H + k8) * 8];
                *(f16x8*)&smem[n * KH + ((k8 ^ (n & 7)) << 3)] = v;
            }
            const _Float16* base0 = (const _Float16*)Xin + (size_t)row0 * F + quad * 8;
            f16x8 q0[F / 32];
#pragma unroll
            for (int i = 0; i < F / 32; ++i)
                q0[i] = *(const f16x8*)(base0 + i * 32);
            __syncthreads();
#pragma unroll
            for (int kq = 0; kq < F / 32; ++kq) {
                f16x8 af0 = q0[kq];
                if (GATHER) af0 = af0 * g0;
                f16x8 bf[8];
#pragma unroll
                for (int j = 0; j < 8; ++j)
                    bf[j] = *(const f16x8*)&smem[(j * 16 + l16) * KH + (((((kq & 3) << 2) + quad) ^ sx) << 3)];
#pragma unroll
                for (int j = 0; j < 8; ++j)
                    acc[j] = __builtin_amdgcn_mfma_f32_16x16x32_f16(af0, bf[j], acc[j], 0, 0, 0);
            }
        }
        __syncthreads();   // done reading W; reuse LDS for epilogue

        _Float16* sC = smem;                  // [64][CPAD]
        const int rw = wave * 16;
#pragma unroll
        for (int j = 0; j < 8; ++j)
#pragma unroll
            for (int g = 0; g < 4; ++g)
                sC[(rw + quad * 4 + g) * CPAD + j * 16 + l16] = (_Float16)acc[j][g];
        __syncthreads();
        {
            int rr = tid >> 2;                // 0..63
            int cc = (tid & 3) * 32;          // 0,32,64,96 halves
            int gr = m_blk + rr;
            if (gr < N) {
                _Float16* Hr = H + (size_t)gr * 128 + cc;
                const _Float16* Sr = sC + rr * CPAD + cc;
#pragma unroll
                for (int c = 0; c < 4; ++c)
                    *(f16x8*)&Hr[c * 8] = *(const f16x8*)&Sr[c * 8];
            }
        }
    } else if (bid < NG + B_GRAPHS) {
        // ---------------- scancsr role (256 threads, LDS overlay) ----------------
        int* ch   = (int*)smem;               // [256]
        int* scnt = ch + 256;                 // [2048]
        int* scur = scnt + 2048;              // [2048]   total 17.4 KB < 32 KB
        int b = bid - NG;
        int base = b * npg;
        int per = (npg + 255) >> 8;
        int s0 = tid * per;
        int s1 = s0 + per; if (s1 > npg) s1 = npg; if (s0 > npg) s0 = npg;
        int s = 0;
        for (int i = s0; i < s1; ++i) { int c = cnt[base + i]; scnt[i] = c; s += c; }
        ch[tid] = s;
        __syncthreads();
        for (int d = 1; d < 256; d <<= 1) {
            int t = ch[tid] + ((tid >= d) ? ch[tid - d] : 0);
            __syncthreads();
            ch[tid] = t;
            __syncthreads();
        }
        int run = b * EPG + ch[tid] - s;
        for (int i = s0; i < s1; ++i) {
            offs[base + i] = run; scur[i] = run;
            run += scnt[i];
        }
        __syncthreads();
        int e0 = b * EPG;
        for (int e = tid; e < EPG; e += 256) {
            float w = ew[e0 + e];
            if (w > 0.f) {
                int sN = esrc[e0 + e], d = edst[e0 + e];
                int pos = atomicAdd(&scur[d - base], 1);
                csr_src[pos] = sN;
                csr_norm[pos] = rsqrtf((float)(scnt[sN - base] + 1)) *
                                rsqrtf((float)(scnt[d - base] + 1));
            }
        }
    } else if (POOL) {
        // ------- pool role: previous layer's readout partials (2 segs/block) -------
        int pb = bid - NG - B_GRAPHS;         // 0..B*RSEG/2-1
        int b = pb >> 4, s2 = pb & 15;        // RSEG/2 = 16 two-seg blocks per graph
        int f = tid & 127, seg = s2 * 2 + (tid >> 7);
        int kprev = npg;                      // rows of previous layer's pool = npg
        int j0 = (kprev * seg) / RSEG, j1 = (kprev * (seg + 1)) / RSEG;
        float mx = -__builtin_inff(), sm = 0.f;
        const _Float16* X = (const _Float16*)Xin;
        for (int j = j0; j < j1; ++j) {
            int g = b * kprev + j;
            float v = (float)X[(size_t)perm[g] * NHID + f] * gate[g];
            mx = fmaxf(mx, v);
            sm += v;
        }
        pmax[(size_t)(b * RSEG + seg) * NHID + f] = mx;
        psum[(size_t)(b * RSEG + seg) * NHID + f] = sm;
    }
}

// -------- aggregation + fused score projection, 8-edge pipeline + XCD swizzle --------
__global__ __launch_bounds__(256) void k_agg(const _Float16* __restrict__ H,
                                             const int* __restrict__ csr_src,
                                             const float* __restrict__ csr_norm,
                                             const int* __restrict__ offs,
                                             const int* __restrict__ cnt,
                                             const float* __restrict__ bias,
                                             const float* __restrict__ Ws,
                                             _Float16* __restrict__ X,
                                             float* __restrict__ hs,
                                             int bpg, int npg) {
    int bi = blockIdx.x;
    int x = bi & 7, s = bi >> 3;
    int gslot = s / bpg, blk = s - gslot * bpg;
    int g = x + 8 * gslot;
    if (g >= B_GRAPHS) return;
    int node = g * npg + blk * 4 + (threadIdx.x >> 6);
    int lane = threadIdx.x & 63;
    int quad = lane >> 4, l16 = lane & 15;

    int st = offs[node], c = cnt[node], en = st + c;
    float acc[8];
#pragma unroll
    for (int j = 0; j < 8; ++j) acc[j] = 0.f;

    if (c > 0) {
        for (int e0 = st; e0 < en; e0 += 8) {
            int eA = e0 + quad, eB = eA + 4;
            int ecA = eA < en ? eA : en - 1;
            int ecB = eB < en ? eB : en - 1;
            int uA = csr_src[ecA], uB = csr_src[ecB];
            float nA = (eA < en) ? csr_norm[ecA] : 0.f;
            float nB = (eB < en) ? csr_norm[ecB] : 0.f;
            f16x8 hA = *(const f16x8*)&H[(size_t)uA * NHID + l16 * 8];
            f16x8 hB = *(const f16x8*)&H[(size_t)uB * NHID + l16 * 8];
#pragma unroll
            for (int j = 0; j < 8; ++j) acc[j] = fmaf((float)hA[j], nA, acc[j]);
#pragma unroll
            for (int j = 0; j < 8; ++j) acc[j] = fmaf((float)hB[j], nB, acc[j]);
        }
    }
#pragma unroll
    for (int j = 0; j < 8; ++j) {
        acc[j] += __shfl_xor(acc[j], 16, 64);
        acc[j] += __shfl_xor(acc[j], 32, 64);
    }
    float invd = 1.f / (float)(c + 1);
    f16x8 hn = *(const f16x8*)&H[(size_t)node * NHID + l16 * 8];
    float4 b0 = *(const float4*)&bias[l16 * 8];
    float4 b1 = *(const float4*)&bias[l16 * 8 + 4];
    float4 w0 = *(const float4*)&Ws[l16 * 8];
    float4 w1 = *(const float4*)&Ws[l16 * 8 + 4];
    const float bb[8] = {b0.x, b0.y, b0.z, b0.w, b1.x, b1.y, b1.z, b1.w};
    const float ww[8] = {w0.x, w0.y, w0.z, w0.w, w1.x, w1.y, w1.z, w1.w};
    float sd = 0.f;
    f16x8 o;
#pragma unroll
    for (int j = 0; j < 8; ++j) {
        float v = fmaxf(acc[j] + (float)hn[j] * invd + bb[j], 0.f);
        o[j] = (_Float16)v;
        sd = fmaf(v, ww[j], sd);
    }
    if (quad == 0)
        *(f16x8*)&X[(size_t)node * NHID + l16 * 8] = o;
    sd += __shfl_xor(sd, 1, 64);
    sd += __shfl_xor(sd, 2, 64);
    sd += __shfl_xor(sd, 4, 64);
    sd += __shfl_xor(sd, 8, 64);
    if (lane == 0) hs[node] = sd;
}

// ------- fused score + per-graph top-k (bitonic) + edge remap (LDS mapping) -------
// Score GCN computed in-block: graph's hs cached in LDS (8 KB), so each edge costs
// 2 global loads (csr_src/csr_norm) + 1 LDS read instead of the old k_score kernel's
// dependent global gather. shs is reused as smap after the score phase.
template<int REMAP>
__global__ __launch_bounds__(1024) void k_scoretopk(const float* __restrict__ hs,
                                                    const int* __restrict__ csr_src,
                                                    const float* __restrict__ csr_norm,
                                                    const int* __restrict__ offs,
                                                    const int* __restrict__ cnt,
                                                    const float* __restrict__ bs,
                                                    int* __restrict__ perm,
                                                    float* __restrict__ gate,
                                                    int* __restrict__ esrc,
                                                    int* __restrict__ edst,
                                                    float* __restrict__ ew,
                                                    int* __restrict__ cntN,
                                                    int npg, int k) {
    __shared__ float ss[2048];
    __shared__ int   si[2048];
    __shared__ float shs[2048];               // hs cache; reused as smap (int) later
    __shared__ int   shist[KMAX];
    int b = blockIdx.x, tid = threadIdx.x;
    int base = b * npg;
    float bs0 = bs[0];
    for (int i = tid; i < 2048; i += 1024)
        shs[i] = (i < npg) ? hs[base + i] : 0.f;
    __syncthreads();
    for (int i = tid; i < 2048; i += 1024) {
        if (i < npg) {
            int st = offs[base + i], c = cnt[base + i];
            float a = 0.f;
            for (int e = st; e < st + c; ++e)
                a = fmaf(shs[csr_src[e] - base], csr_norm[e], a);
            ss[i] = a + shs[i] / (float)(c + 1) + bs0;
        } else {
            ss[i] = -__builtin_inff();
        }
        si[i] = i;
    }
    __syncthreads();
    for (int size = 2; size <= 2048; size <<= 1) {
        for (int stride = size >> 1; stride > 0; stride >>= 1) {
            int t = tid;
            int i = ((t & ~(stride - 1)) << 1) | (t & (stride - 1));
            int j = i | stride;
            float sa = ss[i], sb = ss[j];
            int   ia = si[i], ib = si[j];
            bool b_before_a = (sb > sa) || (sb == sa && ib < ia);
            bool forward = ((i & size) == 0);
            bool doswap = forward ? b_before_a : !b_before_a;
            if (doswap) { ss[i] = sb; ss[j] = sa; si[i] = ib; si[j] = ia; }
            __syncthreads();
        }
    }
    int* smap = (int*)shs;                    // safe: shs dead after score phase
    for (int j = tid; j < npg; j += 1024) {
        int ol = si[j];
        if (j < k) {
            int newg = b * k + j;
            perm[newg] = base + ol;
            smap[ol] = newg;
            gate[newg] = tanhf(ss[j]);
        } else {
            smap[ol] = -1;
        }
    }
    if (REMAP) {
        for (int j = tid; j < k; j += 1024) shist[j] = 0;
        __syncthreads();
        int e0 = b * EPG;
        for (int e = tid; e < EPG; e += 1024) {
            int idx = e0 + e;
            float w = ew[idx];
            bool valid = false;
            int ns = 0, nd = 0;
            if (w > 0.f) {                    // guard BEFORE map lookup
                ns = smap[esrc[idx] - base];
                nd = smap[edst[idx] - base];
                valid = (ns >= 0) && (nd >= 0);
            }
            esrc[idx] = valid ? ns : 0;
            edst[idx] = valid ? nd : 0;
            ew[idx]   = valid ? w : 0.f;
            if (valid) atomicAdd(&shist[nd - b * k], 1);
        }
        __syncthreads();
        for (int j = tid; j < k; j += 1024) cntN[b * k + j] = shist[j];
    }
}

// ---------------- standalone pool partials (layer 2 only) ----------------
__global__ __launch_bounds__(128) void k_pool_readout(const _Float16* __restrict__ X,
                                                      const float* __restrict__ gate,
                                                      const int* __restrict__ perm,
                                                      float* __restrict__ pmax,
                                                      float* __restrict__ psum, int k) {
    int s = blockIdx.x, b = blockIdx.y, f = threadIdx.x;
    int j0 = (k * s) / RSEG, j1 = (k * (s + 1)) / RSEG;
    float mx = -__builtin_inff(), sm = 0.f;
    for (int j = j0; j < j1; ++j) {
        int g = b * k + j;
        int old = perm[g];
        float v = (float)X[(size_t)old * NHID + f] * gate[g];
        mx = fmaxf(mx, v);
        sm += v;
    }
    pmax[(size_t)(b * RSEG + s) * NHID + f] = mx;
    psum[(size_t)(b * RSEG + s) * NHID + f] = sm;
}

__global__ __launch_bounds__(128) void k_readout_comb(const float* __restrict__ pmax,
                                                      const float* __restrict__ psum,
                                                      float* __restrict__ accum, int k) {
    int b = blockIdx.x, f = threadIdx.x;
    float mx = -__builtin_inff(), sm = 0.f;
#pragma unroll
    for (int s = 0; s < RSEG; ++s) {
        mx = fmaxf(mx, pmax[(size_t)(b * RSEG + s) * NHID + f]);
        sm += psum[(size_t)(b * RSEG + s) * NHID + f];
    }
    accum[b * 256 + f]       += mx;
    accum[b * 256 + 128 + f] += sm / (float)k;
}

// ---------------- fused layer-3 readout-combine + final linear ----------------
__global__ __launch_bounds__(128) void k_comb_final(const float* __restrict__ pmax,
                                                    const float* __restrict__ psum,
                                                    const float* __restrict__ accum,
                                                    const float* __restrict__ Wl,
                                                    const float* __restrict__ bl,
                                                    float* __restrict__ out, int k) {
    __shared__ float a[256];
    int b = blockIdx.x, f = threadIdx.x;
    float mx = -__builtin_inff(), sm = 0.f;
#pragma unroll
    for (int s = 0; s < RSEG; ++s) {
        mx = fmaxf(mx, pmax[(size_t)(b * RSEG + s) * NHID + f]);
        sm += psum[(size_t)(b * RSEG + s) * NHID + f];
    }
    a[f]       = accum[b * 256 + f] + mx;
    a[128 + f] = accum[b * 256 + 128 + f] + sm / (float)k;
    __syncthreads();
    float s = bl[f];
    for (int i = 0; i < 256; ++i) s = fmaf(a[i], Wl[i * NHID + f], s);
    out[b * NHID + f] = fmaxf(s, 0.f);
}

extern "C" void kernel_launch(void* const* d_in, const int* in_sizes, int n_in,
                              void* d_out, int out_size, void* d_ws, size_t ws_size,
                              hipStream_t stream) {
    const float* x0 = (const float*)d_in[0];
    const float* Wm[3] = {(const float*)d_in[1], (const float*)d_in[5], (const float*)d_in[9]};
    const float* bm[3] = {(const float*)d_in[2], (const float*)d_in[6], (const float*)d_in[10]};
    const float* Wsc[3] = {(const float*)d_in[3], (const float*)d_in[7], (const float*)d_in[11]};
    const float* bsc[3] = {(const float*)d_in[4], (const float*)d_in[8], (const float*)d_in[12]};
    const float* Wl = (const float*)d_in[13];
    const float* bl = (const float*)d_in[14];
    const int*   ei = (const int*)d_in[15];
    float* out = (float*)d_out;

    _Float16* bufA = (_Float16*)d_ws;                       // N0*128 halves (H)
    _Float16* bufB = bufA + (size_t)N0 * NHID;              // N0*128 (X)
    _Float16* WT1  = bufB + (size_t)N0 * NHID;              // 128*256
    _Float16* WT2  = WT1 + 128 * 256;                       // 128*128
    _Float16* WT3  = WT2 + 128 * 128;                       // 128*128
    float* hs     = (float*)(WT3 + 128 * 128);              // N0
    float* gate   = hs + N0;                                // N0
    float* accum  = gate + N0;                              // B*256
    float* pmax   = accum + B_GRAPHS * 256;                 // B*RSEG*128
    float* psum   = pmax + B_GRAPHS * RSEG * NHID;          // B*RSEG*128
    int*   cntA   = (int*)(psum + B_GRAPHS * RSEG * NHID);  // N0
    int*   cntB   = cntA + N0;                              // N0
    int*   offs   = cntB + N0;                              // N0
    int*   perm   = offs + N0;                              // N0
    int*   esrc   = perm + N0;                              // NE
    int*   edst   = esrc + NE;                              // NE
    float* ew     = (float*)(edst + NE);                    // NE
    int*   csr_src= (int*)(ew + NE);                        // NE
    float* csr_norm = (float*)(csr_src + NE);               // NE

    _Float16* WTs[3] = {WT1, WT2, WT3};
    const int EG = cdiv(NE, 256);
    const int POOLB = B_GRAPHS * (RSEG / 2);   // 800 pool blocks in fat launch

    k_fill_start<<<cdiv(N0, 256), 256, 0, stream>>>(cntA, accum);
    k_init_cvt<<<EG, 256, 0, stream>>>(ei, esrc, edst, ew, cntA,
                                       Wm[0], Wm[1], Wm[2], WT1, WT2, WT3);

    int npg = NPG0;
    _Float16* Hbuf = bufA; _Float16* Xbuf = bufB;

    for (int layer = 0; layer < 3; ++layer) {
        int N = B_GRAPHS * npg;
        int k = (npg * 4) / 5;   // ceil(0.8*n) exact for 2000/1600/1280
        int NG = cdiv(N, 64);
        int bpg = npg >> 2;      // blocks per graph in k_agg
        int* cnt  = (layer == 1) ? cntB : cntA;
        int* cntN = (layer == 1) ? cntA : cntB;

        if (layer == 0) {
            k_fat<1, 256, 0, 0><<<NG + B_GRAPHS, 256, 0, stream>>>(
                x0, WTs[0], perm, gate, Hbuf, N,
                cnt, offs, esrc, edst, ew, csr_src, csr_norm, npg, NG, pmax, psum);
        } else {
            // fat launch also computes previous layer's pool partials (kprev = npg)
            k_fat<0, 128, 1, 1><<<NG + B_GRAPHS + POOLB, 256, 0, stream>>>(
                Xbuf, WTs[layer], perm, gate, Hbuf, N,
                cnt, offs, esrc, edst, ew, csr_src, csr_norm, npg, NG, pmax, psum);
            k_readout_comb<<<B_GRAPHS, 128, 0, stream>>>(pmax, psum, accum, npg);
        }
        k_agg<<<8 * GSLOTS * bpg, 256, 0, stream>>>(Hbuf, csr_src, csr_norm, offs, cnt,
                                                    bm[layer], Wsc[layer], Xbuf, hs, bpg, npg);
        if (layer < 2) {
            k_scoretopk<1><<<B_GRAPHS, 1024, 0, stream>>>(hs, csr_src, csr_norm, offs, cnt,
                                                          bsc[layer], perm, gate,
                                                          esrc, edst, ew, cntN, npg, k);
        } else {
            k_scoretopk<0><<<B_GRAPHS, 1024, 0, stream>>>(hs, csr_src, csr_norm, offs, cnt,
                                                          bsc[layer], perm, gate,
                                                          esrc, edst, ew, cntN, npg, k);
            k_pool_readout<<<dim3(RSEG, B_GRAPHS), 128, 0, stream>>>(Xbuf, gate, perm,
                                                                     pmax, psum, k);
            k_comb_final<<<B_GRAPHS, 128, 0, stream>>>(pmax, psum, accum, Wl, bl, out, k);
        }

        npg = k;
    }
}

// Round 10
// 568.777 us; speedup vs baseline: 1.0240x; 1.0240x over previous
//
#include <hip/hip_runtime.h>
#include <math.h>

#define B_GRAPHS 50
#define NPG0     2000
#define EPG      12000
#define F_IN_C   256
#define NHID     128
#define N0       (B_GRAPHS * NPG0)   // 100000
#define NE       (B_GRAPHS * EPG)    // 600000
#define RSEG     32                  // readout segments per graph (latency-bound gather)
#define GSLOTS   7                   // ceil(50 graphs / 8 XCDs)
#define CPAD     136
#define KMAX     1600                // max next-layer nodes per graph (layer-0 k)

typedef _Float16 f16x8 __attribute__((ext_vector_type(8)));
typedef float    f32x4 __attribute__((ext_vector_type(4)));

static inline int cdiv(int a, int b) { return (a + b - 1) / b; }

// ---------------- startup fill: zero cnt (N0) + accum ----------------
__global__ void k_fill_start(int* __restrict__ cnt, float* __restrict__ accum) {
    int i = blockIdx.x * 256 + threadIdx.x;
    if (i < N0) cnt[i] = 0;
    if (i < B_GRAPHS * 256) accum[i] = 0.f;
}

// ------- edge init + degree count (cnt pre-zeroed) + all weight transposes -------
__global__ void k_init_cvt(const int* __restrict__ ei, int* __restrict__ esrc,
                           int* __restrict__ edst, float* __restrict__ ew,
                           int* __restrict__ cnt,
                           const float* __restrict__ W1, const float* __restrict__ W2,
                           const float* __restrict__ W3, _Float16* __restrict__ WT1,
                           _Float16* __restrict__ WT2, _Float16* __restrict__ WT3) {
    int t = blockIdx.x * 256 + threadIdx.x;
    if (t < NE) {
        int d = ei[NE + t];
        esrc[t] = ei[t]; edst[t] = d; ew[t] = 1.0f;
        atomicAdd(&cnt[d], 1);
    }
    if (t < 128 * 256) {
        int n = t >> 8, kk = t & 255;
        WT1[t] = (_Float16)W1[kk * 128 + n];
    } else if (t < 128 * 256 + 128 * 128) {
        int u = t - 32768; int n = u >> 7, kk = u & 127;
        WT2[u] = (_Float16)W2[kk * 128 + n];
    } else if (t < 128 * 256 + 2 * 128 * 128) {
        int u = t - 49152; int n = u >> 7, kk = u & 127;
        WT3[u] = (_Float16)W3[kk * 128 + n];
    }
}

// ---------------- weight-stationary MFMA GEMM, 64-row M-tile (STANDALONE) ----------------
// Round-7 lesson: fusing helper roles into this kernel collapsed VGPR 100->60 and
// forced spills (WRITE_SIZE +5MB, dur 59->94us). Keep it single-role so the
// allocator serves the GEMM pipeline alone.
template<int FP32IN, int F, int GATHER>
__global__ __launch_bounds__(256) void k_gemm_ws(const void* __restrict__ Xin,
                                                 const _Float16* __restrict__ WT,
                                                 const int* __restrict__ perm,
                                                 const float* __restrict__ gate,
                                                 _Float16* __restrict__ H, int N) {
    constexpr int KH  = (F > 128) ? 128 : F;      // K-cols staged per phase (=128)
    constexpr int K8H = KH / 8;                   // f16x8 chunks per row per phase
    constexpr int SMEMSZ = (128 * KH > 64 * CPAD) ? 128 * KH : 64 * CPAD;
    __shared__ _Float16 smem[SMEMSZ];
    const int tid  = threadIdx.x;
    const int wave = tid >> 6, lane = tid & 63;
    const int quad = lane >> 4, l16 = lane & 15;
    const int m_blk = blockIdx.x * 64;

    f32x4 acc[8];
#pragma unroll
    for (int j = 0; j < 8; ++j) acc[j] = {0.f, 0.f, 0.f, 0.f};

    int row0 = m_blk + wave * 16 + l16;
    if (row0 > N - 1) row0 = N - 1;
    _Float16 g0 = (_Float16)1.0f;
    if (GATHER) {
        g0 = (_Float16)gate[row0];
        row0 = perm[row0];
    }
    const int sx = l16 & 7;
    constexpr int NKQ = F / 32;

    if (FP32IN) {
        constexpr int PD = (NKQ < 4) ? NKQ : 4;
        const float* base0 = (const float*)Xin + (size_t)row0 * F + quad * 8;
        float4 p0[PD][2];
        // A prologue first: HBM loads in flight while we stage W phase 0.
#pragma unroll
        for (int i = 0; i < PD; ++i) {
            p0[i][0] = ((const float4*)(base0 + i * 32))[0];
            p0[i][1] = ((const float4*)(base0 + i * 32))[1];
        }
        // stage W^T phase 0: columns k in [0, KH)
#pragma unroll
        for (int c = tid; c < 128 * K8H; c += 256) {
            int n = c / K8H, k8 = c - n * K8H;
            f16x8 v = *(const f16x8*)&WT[(size_t)(n * (F / 8) + k8) * 8];
            *(f16x8*)&smem[n * KH + ((k8 ^ (n & 7)) << 3)] = v;
        }
        __syncthreads();
#pragma unroll
        for (int kq = 0; kq < NKQ; ++kq) {
            if (KH < F && kq == NKQ / 2) {
                // phase flip: all waves done reading phase 0 -> restage phase 1
                __syncthreads();
#pragma unroll
                for (int c = tid; c < 128 * K8H; c += 256) {
                    int n = c / K8H, k8 = c - n * K8H;
                    f16x8 v = *(const f16x8*)&WT[(size_t)(n * (F / 8) + K8H + k8) * 8];
                    *(f16x8*)&smem[n * KH + ((k8 ^ (n & 7)) << 3)] = v;
                }
                __syncthreads();
            }
            const int b = kq % PD;
            float4 f0 = p0[b][0], f1 = p0[b][1];
            if (kq + PD < NKQ) {
                p0[b][0] = ((const float4*)(base0 + (kq + PD) * 32))[0];
                p0[b][1] = ((const float4*)(base0 + (kq + PD) * 32))[1];
            }
            f16x8 af0 = (f16x8){(_Float16)f0.x,(_Float16)f0.y,(_Float16)f0.z,(_Float16)f0.w,
                                (_Float16)f1.x,(_Float16)f1.y,(_Float16)f1.z,(_Float16)f1.w};
            f16x8 bf[8];
#pragma unroll
            for (int j = 0; j < 8; ++j)
                bf[j] = *(const f16x8*)&smem[(j * 16 + l16) * KH + (((((kq & 3) << 2) + quad) ^ sx) << 3)];
#pragma unroll
            for (int j = 0; j < 8; ++j)
                acc[j] = __builtin_amdgcn_mfma_f32_16x16x32_f16(af0, bf[j], acc[j], 0, 0, 0);
        }
    } else {
        // F=128: single stage, full prefetch — all NKQ loads issued before any MFMA
#pragma unroll
        for (int c = tid; c < 128 * K8H; c += 256) {
            int n = c / K8H, k8 = c - n * K8H;
            f16x8 v = *(const f16x8*)&WT[(size_t)(n * K8H + k8) * 8];
            *(f16x8*)&smem[n * KH + ((k8 ^ (n & 7)) << 3)] = v;
        }
        const _Float16* base0 = (const _Float16*)Xin + (size_t)row0 * F + quad * 8;
        f16x8 q0[NKQ];
#pragma unroll
        for (int i = 0; i < NKQ; ++i)
            q0[i] = *(const f16x8*)(base0 + i * 32);
        __syncthreads();
#pragma unroll
        for (int kq = 0; kq < NKQ; ++kq) {
            f16x8 af0 = q0[kq];
            if (GATHER) af0 = af0 * g0;
            f16x8 bf[8];
#pragma unroll
            for (int j = 0; j < 8; ++j)
                bf[j] = *(const f16x8*)&smem[(j * 16 + l16) * KH + (((((kq & 3) << 2) + quad) ^ sx) << 3)];
#pragma unroll
            for (int j = 0; j < 8; ++j)
                acc[j] = __builtin_amdgcn_mfma_f32_16x16x32_f16(af0, bf[j], acc[j], 0, 0, 0);
        }
    }
    __syncthreads();   // done reading W; reuse LDS for epilogue

    _Float16* sC = smem;                  // [64][CPAD]
    const int rw = wave * 16;
#pragma unroll
    for (int j = 0; j < 8; ++j)
#pragma unroll
        for (int g = 0; g < 4; ++g)
            sC[(rw + quad * 4 + g) * CPAD + j * 16 + l16] = (_Float16)acc[j][g];
    __syncthreads();
    {
        int rr = tid >> 2;                // 0..63
        int cc = (tid & 3) * 32;          // 0,32,64,96 halves
        int gr = m_blk + rr;
        if (gr < N) {
            _Float16* Hr = H + (size_t)gr * 128 + cc;
            const _Float16* Sr = sC + rr * CPAD + cc;
#pragma unroll
            for (int c = 0; c < 4; ++c)
                *(f16x8*)&Hr[c * 8] = *(const f16x8*)&Sr[c * 8];
        }
    }
}

// -------- fused per-graph CSR build: scan (LDS) + edge fill with LDS cursors --------
__global__ __launch_bounds__(1024) void k_scancsr(const int* __restrict__ cnt,
                                                  int* __restrict__ offs,
                                                  const int* __restrict__ esrc,
                                                  const int* __restrict__ edst,
                                                  const float* __restrict__ ew,
                                                  int* __restrict__ csr_src,
                                                  float* __restrict__ csr_norm,
                                                  int npg) {
    __shared__ int ch[1024];
    __shared__ int scnt[2048];
    __shared__ int scur[2048];
    int b = blockIdx.x, tid = threadIdx.x;
    int base = b * npg;
    int per = (npg + 1023) >> 10;                 // =2 for npg<=2000
    int s0 = tid * per;
    int s1 = s0 + per; if (s1 > npg) s1 = npg; if (s0 > npg) s0 = npg;
    int s = 0;
    for (int i = s0; i < s1; ++i) { int c = cnt[base + i]; scnt[i] = c; s += c; }
    ch[tid] = s;
    __syncthreads();
    for (int d = 1; d < 1024; d <<= 1) {
        int t = ch[tid] + ((tid >= d) ? ch[tid - d] : 0);
        __syncthreads();
        ch[tid] = t;
        __syncthreads();
    }
    int run = b * EPG + ch[tid] - s;
    for (int i = s0; i < s1; ++i) {
        offs[base + i] = run; scur[i] = run;
        run += scnt[i];
    }
    __syncthreads();
    // edge fill: this graph's 12000 edges, LDS cursor atomics
    int e0 = b * EPG;
    for (int e = tid; e < EPG; e += 1024) {
        float w = ew[e0 + e];
        if (w > 0.f) {
            int sN = esrc[e0 + e], d = edst[e0 + e];
            int pos = atomicAdd(&scur[d - base], 1);
            csr_src[pos] = sN;
            csr_norm[pos] = rsqrtf((float)(scnt[sN - base] + 1)) *
                            rsqrtf((float)(scnt[d - base] + 1));
        }
    }
}

// -------- aggregation + fused score projection, 8-edge pipeline + XCD swizzle --------
__global__ __launch_bounds__(256) void k_agg(const _Float16* __restrict__ H,
                                             const int* __restrict__ csr_src,
                                             const float* __restrict__ csr_norm,
                                             const int* __restrict__ offs,
                                             const int* __restrict__ cnt,
                                             const float* __restrict__ bias,
                                             const float* __restrict__ Ws,
                                             _Float16* __restrict__ X,
                                             float* __restrict__ hs,
                                             int bpg, int npg) {
    int bi = blockIdx.x;
    int x = bi & 7, s = bi >> 3;
    int gslot = s / bpg, blk = s - gslot * bpg;
    int g = x + 8 * gslot;
    if (g >= B_GRAPHS) return;
    int node = g * npg + blk * 4 + (threadIdx.x >> 6);
    int lane = threadIdx.x & 63;
    int quad = lane >> 4, l16 = lane & 15;

    int st = offs[node], c = cnt[node], en = st + c;
    float acc[8];
#pragma unroll
    for (int j = 0; j < 8; ++j) acc[j] = 0.f;

    if (c > 0) {
        for (int e0 = st; e0 < en; e0 += 8) {
            int eA = e0 + quad, eB = eA + 4;
            int ecA = eA < en ? eA : en - 1;
            int ecB = eB < en ? eB : en - 1;
            int uA = csr_src[ecA], uB = csr_src[ecB];
            float nA = (eA < en) ? csr_norm[ecA] : 0.f;
            float nB = (eB < en) ? csr_norm[ecB] : 0.f;
            f16x8 hA = *(const f16x8*)&H[(size_t)uA * NHID + l16 * 8];
            f16x8 hB = *(const f16x8*)&H[(size_t)uB * NHID + l16 * 8];
#pragma unroll
            for (int j = 0; j < 8; ++j) acc[j] = fmaf((float)hA[j], nA, acc[j]);
#pragma unroll
            for (int j = 0; j < 8; ++j) acc[j] = fmaf((float)hB[j], nB, acc[j]);
        }
    }
#pragma unroll
    for (int j = 0; j < 8; ++j) {
        acc[j] += __shfl_xor(acc[j], 16, 64);
        acc[j] += __shfl_xor(acc[j], 32, 64);
    }
    float invd = 1.f / (float)(c + 1);
    f16x8 hn = *(const f16x8*)&H[(size_t)node * NHID + l16 * 8];
    float4 b0 = *(const float4*)&bias[l16 * 8];
    float4 b1 = *(const float4*)&bias[l16 * 8 + 4];
    float4 w0 = *(const float4*)&Ws[l16 * 8];
    float4 w1 = *(const float4*)&Ws[l16 * 8 + 4];
    const float bb[8] = {b0.x, b0.y, b0.z, b0.w, b1.x, b1.y, b1.z, b1.w};
    const float ww[8] = {w0.x, w0.y, w0.z, w0.w, w1.x, w1.y, w1.z, w1.w};
    float sd = 0.f;
    f16x8 o;
#pragma unroll
    for (int j = 0; j < 8; ++j) {
        float v = fmaxf(acc[j] + (float)hn[j] * invd + bb[j], 0.f);
        o[j] = (_Float16)v;
        sd = fmaf(v, ww[j], sd);
    }
    if (quad == 0)
        *(f16x8*)&X[(size_t)node * NHID + l16 * 8] = o;
    sd += __shfl_xor(sd, 1, 64);
    sd += __shfl_xor(sd, 2, 64);
    sd += __shfl_xor(sd, 4, 64);
    sd += __shfl_xor(sd, 8, 64);
    if (lane == 0) hs[node] = sd;
}

// ------- fused score + per-graph top-k (bitonic) + edge remap (LDS mapping) -------
// Score GCN computed in-block: graph's hs cached in LDS (8 KB), each edge = 2 global
// loads + 1 LDS read (replaces the standalone k_score kernel's dependent gather).
// shs reused as smap after the score phase.
template<int REMAP>
__global__ __launch_bounds__(1024) void k_scoretopk(const float* __restrict__ hs,
                                                    const int* __restrict__ csr_src,
                                                    const float* __restrict__ csr_norm,
                                                    const int* __restrict__ offs,
                                                    const int* __restrict__ cnt,
                                                    const float* __restrict__ bs,
                                                    int* __restrict__ perm,
                                                    float* __restrict__ gate,
                                                    int* __restrict__ esrc,
                                                    int* __restrict__ edst,
                                                    float* __restrict__ ew,
                                                    int* __restrict__ cntN,
                                                    int npg, int k) {
    __shared__ float ss[2048];
    __shared__ int   si[2048];
    __shared__ float shs[2048];               // hs cache; reused as smap (int) later
    __shared__ int   shist[KMAX];
    int b = blockIdx.x, tid = threadIdx.x;
    int base = b * npg;
    float bs0 = bs[0];
    for (int i = tid; i < 2048; i += 1024)
        shs[i] = (i < npg) ? hs[base + i] : 0.f;
    __syncthreads();
    for (int i = tid; i < 2048; i += 1024) {
        if (i < npg) {
            int st = offs[base + i], c = cnt[base + i];
            float a = 0.f;
            for (int e = st; e < st + c; ++e)
                a = fmaf(shs[csr_src[e] - base], csr_norm[e], a);
            ss[i] = a + shs[i] / (float)(c + 1) + bs0;
        } else {
            ss[i] = -__builtin_inff();
        }
        si[i] = i;
    }
    __syncthreads();
    for (int size = 2; size <= 2048; size <<= 1) {
        for (int stride = size >> 1; stride > 0; stride >>= 1) {
            int t = tid;
            int i = ((t & ~(stride - 1)) << 1) | (t & (stride - 1));
            int j = i | stride;
            float sa = ss[i], sb = ss[j];
            int   ia = si[i], ib = si[j];
            bool b_before_a = (sb > sa) || (sb == sa && ib < ia);
            bool forward = ((i & size) == 0);
            bool doswap = forward ? b_before_a : !b_before_a;
            if (doswap) { ss[i] = sb; ss[j] = sa; si[i] = ib; si[j] = ia; }
            __syncthreads();
        }
    }
    int* smap = (int*)shs;                    // safe: shs dead after score phase
    for (int j = tid; j < npg; j += 1024) {
        int ol = si[j];
        if (j < k) {
            int newg = b * k + j;
            perm[newg] = base + ol;
            smap[ol] = newg;
            gate[newg] = tanhf(ss[j]);
        } else {
            smap[ol] = -1;
        }
    }
    if (REMAP) {
        for (int j = tid; j < k; j += 1024) shist[j] = 0;
        __syncthreads();
        int e0 = b * EPG;
        for (int e = tid; e < EPG; e += 1024) {
            int idx = e0 + e;
            float w = ew[idx];
            bool valid = false;
            int ns = 0, nd = 0;
            if (w > 0.f) {                    // guard BEFORE map lookup
                ns = smap[esrc[idx] - base];
                nd = smap[edst[idx] - base];
                valid = (ns >= 0) && (nd >= 0);
            }
            esrc[idx] = valid ? ns : 0;
            edst[idx] = valid ? nd : 0;
            ew[idx]   = valid ? w : 0.f;
            if (valid) atomicAdd(&shist[nd - b * k], 1);
        }
        __syncthreads();
        for (int j = tid; j < k; j += 1024) cntN[b * k + j] = shist[j];
    }
}

// ---------------- partial readout over pooled rows (no XP materialization) ----------------
__global__ __launch_bounds__(128) void k_pool_readout(const _Float16* __restrict__ X,
                                                      const float* __restrict__ gate,
                                                      const int* __restrict__ perm,
                                                      float* __restrict__ pmax,
                                                      float* __restrict__ psum, int k) {
    int s = blockIdx.x, b = blockIdx.y, f = threadIdx.x;
    int j0 = (k * s) / RSEG, j1 = (k * (s + 1)) / RSEG;
    float mx = -__builtin_inff(), sm = 0.f;
    for (int j = j0; j < j1; ++j) {
        int g = b * k + j;
        int old = perm[g];
        float v = (float)X[(size_t)old * NHID + f] * gate[g];
        mx = fmaxf(mx, v);
        sm += v;
    }
    pmax[(size_t)(b * RSEG + s) * NHID + f] = mx;
    psum[(size_t)(b * RSEG + s) * NHID + f] = sm;
}

__global__ __launch_bounds__(128) void k_readout_comb(const float* __restrict__ pmax,
                                                      const float* __restrict__ psum,
                                                      float* __restrict__ accum, int k) {
    int b = blockIdx.x, f = threadIdx.x;
    float mx = -__builtin_inff(), sm = 0.f;
#pragma unroll
    for (int s = 0; s < RSEG; ++s) {
        mx = fmaxf(mx, pmax[(size_t)(b * RSEG + s) * NHID + f]);
        sm += psum[(size_t)(b * RSEG + s) * NHID + f];
    }
    accum[b * 256 + f]       += mx;
    accum[b * 256 + 128 + f] += sm / (float)k;
}

// ---------------- fused layer-3 readout-combine + final linear ----------------
__global__ __launch_bounds__(128) void k_comb_final(const float* __restrict__ pmax,
                                                    const float* __restrict__ psum,
                                                    const float* __restrict__ accum,
                                                    const float* __restrict__ Wl,
                                                    const float* __restrict__ bl,
                                                    float* __restrict__ out, int k) {
    __shared__ float a[256];
    int b = blockIdx.x, f = threadIdx.x;
    float mx = -__builtin_inff(), sm = 0.f;
#pragma unroll
    for (int s = 0; s < RSEG; ++s) {
        mx = fmaxf(mx, pmax[(size_t)(b * RSEG + s) * NHID + f]);
        sm += psum[(size_t)(b * RSEG + s) * NHID + f];
    }
    a[f]       = accum[b * 256 + f] + mx;
    a[128 + f] = accum[b * 256 + 128 + f] + sm / (float)k;
    __syncthreads();
    float s = bl[f];
    for (int i = 0; i < 256; ++i) s = fmaf(a[i], Wl[i * NHID + f], s);
    out[b * NHID + f] = fmaxf(s, 0.f);
}

extern "C" void kernel_launch(void* const* d_in, const int* in_sizes, int n_in,
                              void* d_out, int out_size, void* d_ws, size_t ws_size,
                              hipStream_t stream) {
    const float* x0 = (const float*)d_in[0];
    const float* Wm[3] = {(const float*)d_in[1], (const float*)d_in[5], (const float*)d_in[9]};
    const float* bm[3] = {(const float*)d_in[2], (const float*)d_in[6], (const float*)d_in[10]};
    const float* Wsc[3] = {(const float*)d_in[3], (const float*)d_in[7], (const float*)d_in[11]};
    const float* bsc[3] = {(const float*)d_in[4], (const float*)d_in[8], (const float*)d_in[12]};
    const float* Wl = (const float*)d_in[13];
    const float* bl = (const float*)d_in[14];
    const int*   ei = (const int*)d_in[15];
    float* out = (float*)d_out;

    _Float16* bufA = (_Float16*)d_ws;                       // N0*128 halves (H)
    _Float16* bufB = bufA + (size_t)N0 * NHID;              // N0*128 (X)
    _Float16* WT1  = bufB + (size_t)N0 * NHID;              // 128*256
    _Float16* WT2  = WT1 + 128 * 256;                       // 128*128
    _Float16* WT3  = WT2 + 128 * 128;                       // 128*128
    float* hs     = (float*)(WT3 + 128 * 128);              // N0
    float* gate   = hs + N0;                                // N0
    float* accum  = gate + N0;                              // B*256
    float* pmax   = accum + B_GRAPHS * 256;                 // B*RSEG*128
    float* psum   = pmax + B_GRAPHS * RSEG * NHID;          // B*RSEG*128
    int*   cntA   = (int*)(psum + B_GRAPHS * RSEG * NHID);  // N0
    int*   cntB   = cntA + N0;                              // N0
    int*   offs   = cntB + N0;                              // N0
    int*   perm   = offs + N0;                              // N0
    int*   esrc   = perm + N0;                              // NE
    int*   edst   = esrc + NE;                              // NE
    float* ew     = (float*)(edst + NE);                    // NE
    int*   csr_src= (int*)(ew + NE);                        // NE
    float* csr_norm = (float*)(csr_src + NE);               // NE

    _Float16* WTs[3] = {WT1, WT2, WT3};
    const int EG = cdiv(NE, 256);

    k_fill_start<<<cdiv(N0, 256), 256, 0, stream>>>(cntA, accum);
    k_init_cvt<<<EG, 256, 0, stream>>>(ei, esrc, edst, ew, cntA,
                                       Wm[0], Wm[1], Wm[2], WT1, WT2, WT3);

    int npg = NPG0;
    _Float16* Hbuf = bufA; _Float16* Xbuf = bufB;

    for (int layer = 0; layer < 3; ++layer) {
        int N = B_GRAPHS * npg;
        int k = (npg * 4) / 5;   // ceil(0.8*n) exact for 2000/1600/1280
        int bpg = npg >> 2;      // blocks per graph in k_agg
        int* cnt  = (layer == 1) ? cntB : cntA;
        int* cntN = (layer == 1) ? cntA : cntB;

        if (layer == 0)
            k_gemm_ws<1, 256, 0><<<cdiv(N, 64), 256, 0, stream>>>(x0, WTs[0], perm, gate, Hbuf, N);
        else
            k_gemm_ws<0, 128, 1><<<cdiv(N, 64), 256, 0, stream>>>(Xbuf, WTs[layer], perm, gate, Hbuf, N);
        k_scancsr<<<B_GRAPHS, 1024, 0, stream>>>(cnt, offs, esrc, edst, ew,
                                                 csr_src, csr_norm, npg);
        k_agg<<<8 * GSLOTS * bpg, 256, 0, stream>>>(Hbuf, csr_src, csr_norm, offs, cnt,
                                                    bm[layer], Wsc[layer], Xbuf, hs, bpg, npg);
        if (layer < 2) {
            k_scoretopk<1><<<B_GRAPHS, 1024, 0, stream>>>(hs, csr_src, csr_norm, offs, cnt,
                                                          bsc[layer], perm, gate,
                                                          esrc, edst, ew, cntN, npg, k);
        } else {
            k_scoretopk<0><<<B_GRAPHS, 1024, 0, stream>>>(hs, csr_src, csr_norm, offs, cnt,
                                                          bsc[layer], perm, gate,
                                                          esrc, edst, ew, cntN, npg, k);
        }
        k_pool_readout<<<dim3(RSEG, B_GRAPHS), 128, 0, stream>>>(Xbuf, gate, perm, pmax, psum, k);
        if (layer < 2) {
            k_readout_comb<<<B_GRAPHS, 128, 0, stream>>>(pmax, psum, accum, k);
        } else {
            k_comb_final<<<B_GRAPHS, 128, 0, stream>>>(pmax, psum, accum, Wl, bl, out, k);
        }

        npg = k;
    }
}

// Round 11
// 549.596 us; speedup vs baseline: 1.0597x; 1.0349x over previous
//
#include <hip/hip_runtime.h>
#include <math.h>

#define B_GRAPHS 50
#define NPG0     2000
#define EPG      12000
#define F_IN_C   256
#define NHID     128
#define N0       (B_GRAPHS * NPG0)   // 100000
#define NE       (B_GRAPHS * EPG)    // 600000
#define RSEG     32                  // readout segments per graph (latency-bound gather)
#define GSLOTS   7                   // ceil(50 graphs / 8 XCDs)
#define CPAD     136
#define KMAX     1600                // max next-layer nodes per graph (layer-0 k)

typedef _Float16 f16x8 __attribute__((ext_vector_type(8)));
typedef float    f32x4 __attribute__((ext_vector_type(4)));

static inline int cdiv(int a, int b) { return (a + b - 1) / b; }

// ---------------- startup fill: zero cnt (N0) + accum ----------------
__global__ void k_fill_start(int* __restrict__ cnt, float* __restrict__ accum) {
    int i = blockIdx.x * 256 + threadIdx.x;
    if (i < N0) cnt[i] = 0;
    if (i < B_GRAPHS * 256) accum[i] = 0.f;
}

// ------- edge init + degree count (cnt pre-zeroed) + all weight transposes -------
__global__ void k_init_cvt(const int* __restrict__ ei, int* __restrict__ esrc,
                           int* __restrict__ edst, float* __restrict__ ew,
                           int* __restrict__ cnt,
                           const float* __restrict__ W1, const float* __restrict__ W2,
                           const float* __restrict__ W3, _Float16* __restrict__ WT1,
                           _Float16* __restrict__ WT2, _Float16* __restrict__ WT3) {
    int t = blockIdx.x * 256 + threadIdx.x;
    if (t < NE) {
        int d = ei[NE + t];
        esrc[t] = ei[t]; edst[t] = d; ew[t] = 1.0f;
        atomicAdd(&cnt[d], 1);
    }
    if (t < 128 * 256) {
        int n = t >> 8, kk = t & 255;
        WT1[t] = (_Float16)W1[kk * 128 + n];
    } else if (t < 128 * 256 + 128 * 128) {
        int u = t - 32768; int n = u >> 7, kk = u & 127;
        WT2[u] = (_Float16)W2[kk * 128 + n];
    } else if (t < 128 * 256 + 2 * 128 * 128) {
        int u = t - 49152; int n = u >> 7, kk = u & 127;
        WT3[u] = (_Float16)W3[kk * 128 + n];
    }
}

// ---------------- weight-stationary MFMA GEMM, 64-row M-tile (STANDALONE) ----------------
// Round-7 lesson: fusing helper roles into this kernel collapsed VGPR 100->60 and
// forced spills. Keep it single-role so the allocator serves the GEMM pipeline alone.
template<int FP32IN, int F, int GATHER>
__global__ __launch_bounds__(256) void k_gemm_ws(const void* __restrict__ Xin,
                                                 const _Float16* __restrict__ WT,
                                                 const int* __restrict__ perm,
                                                 const float* __restrict__ gate,
                                                 _Float16* __restrict__ H, int N) {
    constexpr int KH  = (F > 128) ? 128 : F;      // K-cols staged per phase (=128)
    constexpr int K8H = KH / 8;                   // f16x8 chunks per row per phase
    constexpr int SMEMSZ = (128 * KH > 64 * CPAD) ? 128 * KH : 64 * CPAD;
    __shared__ _Float16 smem[SMEMSZ];
    const int tid  = threadIdx.x;
    const int wave = tid >> 6, lane = tid & 63;
    const int quad = lane >> 4, l16 = lane & 15;
    const int m_blk = blockIdx.x * 64;

    f32x4 acc[8];
#pragma unroll
    for (int j = 0; j < 8; ++j) acc[j] = {0.f, 0.f, 0.f, 0.f};

    int row0 = m_blk + wave * 16 + l16;
    if (row0 > N - 1) row0 = N - 1;
    _Float16 g0 = (_Float16)1.0f;
    if (GATHER) {
        g0 = (_Float16)gate[row0];
        row0 = perm[row0];
    }
    const int sx = l16 & 7;
    constexpr int NKQ = F / 32;

    if (FP32IN) {
        constexpr int PD = (NKQ < 4) ? NKQ : 4;
        const float* base0 = (const float*)Xin + (size_t)row0 * F + quad * 8;
        float4 p0[PD][2];
        // A prologue first: HBM loads in flight while we stage W phase 0.
#pragma unroll
        for (int i = 0; i < PD; ++i) {
            p0[i][0] = ((const float4*)(base0 + i * 32))[0];
            p0[i][1] = ((const float4*)(base0 + i * 32))[1];
        }
        // stage W^T phase 0: columns k in [0, KH)
#pragma unroll
        for (int c = tid; c < 128 * K8H; c += 256) {
            int n = c / K8H, k8 = c - n * K8H;
            f16x8 v = *(const f16x8*)&WT[(size_t)(n * (F / 8) + k8) * 8];
            *(f16x8*)&smem[n * KH + ((k8 ^ (n & 7)) << 3)] = v;
        }
        __syncthreads();
#pragma unroll
        for (int kq = 0; kq < NKQ; ++kq) {
            if (KH < F && kq == NKQ / 2) {
                // phase flip: all waves done reading phase 0 -> restage phase 1
                __syncthreads();
#pragma unroll
                for (int c = tid; c < 128 * K8H; c += 256) {
                    int n = c / K8H, k8 = c - n * K8H;
                    f16x8 v = *(const f16x8*)&WT[(size_t)(n * (F / 8) + K8H + k8) * 8];
                    *(f16x8*)&smem[n * KH + ((k8 ^ (n & 7)) << 3)] = v;
                }
                __syncthreads();
            }
            const int b = kq % PD;
            float4 f0 = p0[b][0], f1 = p0[b][1];
            if (kq + PD < NKQ) {
                p0[b][0] = ((const float4*)(base0 + (kq + PD) * 32))[0];
                p0[b][1] = ((const float4*)(base0 + (kq + PD) * 32))[1];
            }
            f16x8 af0 = (f16x8){(_Float16)f0.x,(_Float16)f0.y,(_Float16)f0.z,(_Float16)f0.w,
                                (_Float16)f1.x,(_Float16)f1.y,(_Float16)f1.z,(_Float16)f1.w};
            f16x8 bf[8];
#pragma unroll
            for (int j = 0; j < 8; ++j)
                bf[j] = *(const f16x8*)&smem[(j * 16 + l16) * KH + (((((kq & 3) << 2) + quad) ^ sx) << 3)];
#pragma unroll
            for (int j = 0; j < 8; ++j)
                acc[j] = __builtin_amdgcn_mfma_f32_16x16x32_f16(af0, bf[j], acc[j], 0, 0, 0);
        }
    } else {
        // F=128: single stage, full prefetch — all NKQ loads issued before any MFMA
#pragma unroll
        for (int c = tid; c < 128 * K8H; c += 256) {
            int n = c / K8H, k8 = c - n * K8H;
            f16x8 v = *(const f16x8*)&WT[(size_t)(n * K8H + k8) * 8];
            *(f16x8*)&smem[n * KH + ((k8 ^ (n & 7)) << 3)] = v;
        }
        const _Float16* base0 = (const _Float16*)Xin + (size_t)row0 * F + quad * 8;
        f16x8 q0[NKQ];
#pragma unroll
        for (int i = 0; i < NKQ; ++i)
            q0[i] = *(const f16x8*)(base0 + i * 32);
        __syncthreads();
#pragma unroll
        for (int kq = 0; kq < NKQ; ++kq) {
            f16x8 af0 = q0[kq];
            if (GATHER) af0 = af0 * g0;
            f16x8 bf[8];
#pragma unroll
            for (int j = 0; j < 8; ++j)
                bf[j] = *(const f16x8*)&smem[(j * 16 + l16) * KH + (((((kq & 3) << 2) + quad) ^ sx) << 3)];
#pragma unroll
            for (int j = 0; j < 8; ++j)
                acc[j] = __builtin_amdgcn_mfma_f32_16x16x32_f16(af0, bf[j], acc[j], 0, 0, 0);
        }
    }
    __syncthreads();   // done reading W; reuse LDS for epilogue

    _Float16* sC = smem;                  // [64][CPAD]
    const int rw = wave * 16;
#pragma unroll
    for (int j = 0; j < 8; ++j)
#pragma unroll
        for (int g = 0; g < 4; ++g)
            sC[(rw + quad * 4 + g) * CPAD + j * 16 + l16] = (_Float16)acc[j][g];
    __syncthreads();
    {
        int rr = tid >> 2;                // 0..63
        int cc = (tid & 3) * 32;          // 0,32,64,96 halves
        int gr = m_blk + rr;
        if (gr < N) {
            _Float16* Hr = H + (size_t)gr * 128 + cc;
            const _Float16* Sr = sC + rr * CPAD + cc;
#pragma unroll
            for (int c = 0; c < 4; ++c)
                *(f16x8*)&Hr[c * 8] = *(const f16x8*)&Sr[c * 8];
        }
    }
}

// -------- per-graph CSR build for LAYER 0 only (scan + LDS-cursor edge fill) --------
__global__ __launch_bounds__(1024) void k_scancsr(const int* __restrict__ cnt,
                                                  int* __restrict__ offs,
                                                  const int* __restrict__ esrc,
                                                  const int* __restrict__ edst,
                                                  const float* __restrict__ ew,
                                                  int* __restrict__ csr_src,
                                                  float* __restrict__ csr_norm,
                                                  int npg) {
    __shared__ int ch[1024];
    __shared__ int scnt[2048];
    __shared__ int scur[2048];
    int b = blockIdx.x, tid = threadIdx.x;
    int base = b * npg;
    int per = (npg + 1023) >> 10;                 // =2 for npg<=2000
    int s0 = tid * per;
    int s1 = s0 + per; if (s1 > npg) s1 = npg; if (s0 > npg) s0 = npg;
    int s = 0;
    for (int i = s0; i < s1; ++i) { int c = cnt[base + i]; scnt[i] = c; s += c; }
    ch[tid] = s;
    __syncthreads();
    for (int d = 1; d < 1024; d <<= 1) {
        int t = ch[tid] + ((tid >= d) ? ch[tid - d] : 0);
        __syncthreads();
        ch[tid] = t;
        __syncthreads();
    }
    int run = b * EPG + ch[tid] - s;
    for (int i = s0; i < s1; ++i) {
        offs[base + i] = run; scur[i] = run;
        run += scnt[i];
    }
    __syncthreads();
    int e0 = b * EPG;
    for (int e = tid; e < EPG; e += 1024) {
        float w = ew[e0 + e];
        if (w > 0.f) {
            int sN = esrc[e0 + e], d = edst[e0 + e];
            int pos = atomicAdd(&scur[d - base], 1);
            csr_src[pos] = sN;
            csr_norm[pos] = rsqrtf((float)(scnt[sN - base] + 1)) *
                            rsqrtf((float)(scnt[d - base] + 1));
        }
    }
}

// -------- aggregation + fused score projection, 8-edge pipeline + XCD swizzle --------
__global__ __launch_bounds__(256) void k_agg(const _Float16* __restrict__ H,
                                             const int* __restrict__ csr_src,
                                             const float* __restrict__ csr_norm,
                                             const int* __restrict__ offs,
                                             const int* __restrict__ cnt,
                                             const float* __restrict__ bias,
                                             const float* __restrict__ Ws,
                                             _Float16* __restrict__ X,
                                             float* __restrict__ hs,
                                             int bpg, int npg) {
    int bi = blockIdx.x;
    int x = bi & 7, s = bi >> 3;
    int gslot = s / bpg, blk = s - gslot * bpg;
    int g = x + 8 * gslot;
    if (g >= B_GRAPHS) return;
    int node = g * npg + blk * 4 + (threadIdx.x >> 6);
    int lane = threadIdx.x & 63;
    int quad = lane >> 4, l16 = lane & 15;

    int st = offs[node], c = cnt[node], en = st + c;
    float acc[8];
#pragma unroll
    for (int j = 0; j < 8; ++j) acc[j] = 0.f;

    if (c > 0) {
        for (int e0 = st; e0 < en; e0 += 8) {
            int eA = e0 + quad, eB = eA + 4;
            int ecA = eA < en ? eA : en - 1;
            int ecB = eB < en ? eB : en - 1;
            int uA = csr_src[ecA], uB = csr_src[ecB];
            float nA = (eA < en) ? csr_norm[ecA] : 0.f;
            float nB = (eB < en) ? csr_norm[ecB] : 0.f;
            f16x8 hA = *(const f16x8*)&H[(size_t)uA * NHID + l16 * 8];
            f16x8 hB = *(const f16x8*)&H[(size_t)uB * NHID + l16 * 8];
#pragma unroll
            for (int j = 0; j < 8; ++j) acc[j] = fmaf((float)hA[j], nA, acc[j]);
#pragma unroll
            for (int j = 0; j < 8; ++j) acc[j] = fmaf((float)hB[j], nB, acc[j]);
        }
    }
#pragma unroll
    for (int j = 0; j < 8; ++j) {
        acc[j] += __shfl_xor(acc[j], 16, 64);
        acc[j] += __shfl_xor(acc[j], 32, 64);
    }
    float invd = 1.f / (float)(c + 1);
    f16x8 hn = *(const f16x8*)&H[(size_t)node * NHID + l16 * 8];
    float4 b0 = *(const float4*)&bias[l16 * 8];
    float4 b1 = *(const float4*)&bias[l16 * 8 + 4];
    float4 w0 = *(const float4*)&Ws[l16 * 8];
    float4 w1 = *(const float4*)&Ws[l16 * 8 + 4];
    const float bb[8] = {b0.x, b0.y, b0.z, b0.w, b1.x, b1.y, b1.z, b1.w};
    const float ww[8] = {w0.x, w0.y, w0.z, w0.w, w1.x, w1.y, w1.z, w1.w};
    float sd = 0.f;
    f16x8 o;
#pragma unroll
    for (int j = 0; j < 8; ++j) {
        float v = fmaxf(acc[j] + (float)hn[j] * invd + bb[j], 0.f);
        o[j] = (_Float16)v;
        sd = fmaf(v, ww[j], sd);
    }
    if (quad == 0)
        *(f16x8*)&X[(size_t)node * NHID + l16 * 8] = o;
    sd += __shfl_xor(sd, 1, 64);
    sd += __shfl_xor(sd, 2, 64);
    sd += __shfl_xor(sd, 4, 64);
    sd += __shfl_xor(sd, 8, 64);
    if (lane == 0) hs[node] = sd;
}

// --- fused: [COMB: fold prev-layer readout partials] + score + top-k + remap
//     + [REMAP: next-layer CSR build (prefix-scan + LDS-cursor fill)] ---
// All merges are block-local: block b exclusively owns graph b's data.
// LDS reuse chain: ss/si (bitonic) -> sscan/scur (CSR scan+cursors); shs -> smap.
template<int REMAP, int COMB>
__global__ __launch_bounds__(1024) void k_scoretopk(const float* __restrict__ hs,
                                                    int* __restrict__ csr_src,
                                                    float* __restrict__ csr_norm,
                                                    int* __restrict__ offs,
                                                    const int* __restrict__ cnt,
                                                    const float* __restrict__ bs,
                                                    int* __restrict__ perm,
                                                    float* __restrict__ gate,
                                                    int* __restrict__ esrc,
                                                    int* __restrict__ edst,
                                                    float* __restrict__ ew,
                                                    int* __restrict__ cntN,
                                                    const float* __restrict__ pmax,
                                                    const float* __restrict__ psum,
                                                    float* __restrict__ accum,
                                                    int npg, int k) {
    __shared__ float ss[2048];
    __shared__ int   si[2048];
    __shared__ float shs[2048];               // hs cache; reused as smap (int) later
    __shared__ int   shist[KMAX];
    int b = blockIdx.x, tid = threadIdx.x;
    int base = b * npg;

    if (COMB) {
        // fold previous layer's readout partials into accum (pool of prev layer
        // completed 3 launches ago; this block owns graph b exclusively).
        // prev-layer row count == npg (current layer's node count).
        if (tid < 2 * NHID) {
            int f = tid & 127;
            bool isSum = tid >= NHID;
            float a2 = isSum ? 0.f : -__builtin_inff();
            for (int s = 0; s < RSEG; ++s) {
                float v = (isSum ? psum : pmax)[(size_t)(b * RSEG + s) * NHID + f];
                a2 = isSum ? (a2 + v) : fmaxf(a2, v);
            }
            if (isSum) accum[b * 256 + 128 + f] += a2 / (float)npg;
            else       accum[b * 256 + f]       += a2;
        }
    }

    float bs0 = bs[0];
    for (int i = tid; i < 2048; i += 1024)
        shs[i] = (i < npg) ? hs[base + i] : 0.f;
    __syncthreads();
    for (int i = tid; i < 2048; i += 1024) {
        if (i < npg) {
            int st = offs[base + i], c = cnt[base + i];
            float a = 0.f;
            for (int e = st; e < st + c; ++e)
                a = fmaf(shs[csr_src[e] - base], csr_norm[e], a);
            ss[i] = a + shs[i] / (float)(c + 1) + bs0;
        } else {
            ss[i] = -__builtin_inff();
        }
        si[i] = i;
    }
    __syncthreads();
    for (int size = 2; size <= 2048; size <<= 1) {
        for (int stride = size >> 1; stride > 0; stride >>= 1) {
            int t = tid;
            int i = ((t & ~(stride - 1)) << 1) | (t & (stride - 1));
            int j = i | stride;
            float sa = ss[i], sb = ss[j];
            int   ia = si[i], ib = si[j];
            bool b_before_a = (sb > sa) || (sb == sa && ib < ia);
            bool forward = ((i & size) == 0);
            bool doswap = forward ? b_before_a : !b_before_a;
            if (doswap) { ss[i] = sb; ss[j] = sa; si[i] = ib; si[j] = ia; }
            __syncthreads();
        }
    }
    int* smap = (int*)shs;                    // safe: shs dead after score phase
    for (int j = tid; j < npg; j += 1024) {
        int ol = si[j];
        if (j < k) {
            int newg = b * k + j;
            perm[newg] = base + ol;
            smap[ol] = newg;
            gate[newg] = tanhf(ss[j]);
        } else {
            smap[ol] = -1;
        }
    }
    if (REMAP) {
        for (int j = tid; j < k; j += 1024) shist[j] = 0;
        __syncthreads();                      // also fences output-phase ss/si reads
        int e0 = b * EPG;
        for (int e = tid; e < EPG; e += 1024) {
            int idx = e0 + e;
            float w = ew[idx];
            bool valid = false;
            int ns = 0, nd = 0;
            if (w > 0.f) {                    // guard BEFORE map lookup
                ns = smap[esrc[idx] - base];
                nd = smap[edst[idx] - base];
                valid = (ns >= 0) && (nd >= 0);
            }
            esrc[idx] = valid ? ns : 0;
            edst[idx] = valid ? nd : 0;
            ew[idx]   = valid ? w : 0.f;
            if (valid) atomicAdd(&shist[nd - b * k], 1);
        }
        __syncthreads();                      // shist final; ss/si free for reuse
        // ---- next-layer CSR build: prefix-scan shist -> offs/cursors, then fill ----
        int* sscan = (int*)ss;                // scan scratch
        int* scur  = si;                      // per-node cursors
        int per2 = (k + 1023) >> 10;          // =2 for k<=1600
        int t0 = tid * per2, t1 = t0 + per2;
        if (t1 > k) t1 = k; if (t0 > k) t0 = k;
        int sloc = 0;
        for (int i = t0; i < t1; ++i) sloc += shist[i];
        sscan[tid] = sloc;
        __syncthreads();
        for (int d = 1; d < 1024; d <<= 1) {
            int t = sscan[tid] + ((tid >= d) ? sscan[tid - d] : 0);
            __syncthreads();
            sscan[tid] = t;
            __syncthreads();
        }
        int run = b * EPG + sscan[tid] - sloc;
        for (int i = t0; i < t1; ++i) {
            offs[b * k + i] = run; scur[i] = run;
            cntN[b * k + i] = shist[i];
            run += shist[i];
        }
        __syncthreads();
        // fill pass: re-read remapped edges (block-local, L2-hot), LDS cursor atomics
        for (int e = tid; e < EPG; e += 1024) {
            int idx = e0 + e;
            float w = ew[idx];
            if (w > 0.f) {
                int ns = esrc[idx], nd = edst[idx];
                int pos = atomicAdd(&scur[nd - b * k], 1);
                csr_src[pos] = ns;
                csr_norm[pos] = rsqrtf((float)(shist[ns - b * k] + 1)) *
                                rsqrtf((float)(shist[nd - b * k] + 1));
            }
        }
    }
}

// ---------------- partial readout over pooled rows (no XP materialization) ----------------
__global__ __launch_bounds__(128) void k_pool_readout(const _Float16* __restrict__ X,
                                                      const float* __restrict__ gate,
                                                      const int* __restrict__ perm,
                                                      float* __restrict__ pmax,
                                                      float* __restrict__ psum, int k) {
    int s = blockIdx.x, b = blockIdx.y, f = threadIdx.x;
    int j0 = (k * s) / RSEG, j1 = (k * (s + 1)) / RSEG;
    float mx = -__builtin_inff(), sm = 0.f;
    for (int j = j0; j < j1; ++j) {
        int g = b * k + j;
        int old = perm[g];
        float v = (float)X[(size_t)old * NHID + f] * gate[g];
        mx = fmaxf(mx, v);
        sm += v;
    }
    pmax[(size_t)(b * RSEG + s) * NHID + f] = mx;
    psum[(size_t)(b * RSEG + s) * NHID + f] = sm;
}

// ---------------- fused layer-3 readout-combine + final linear ----------------
__global__ __launch_bounds__(128) void k_comb_final(const float* __restrict__ pmax,
                                                    const float* __restrict__ psum,
                                                    const float* __restrict__ accum,
                                                    const float* __restrict__ Wl,
                                                    const float* __restrict__ bl,
                                                    float* __restrict__ out, int k) {
    __shared__ float a[256];
    int b = blockIdx.x, f = threadIdx.x;
    float mx = -__builtin_inff(), sm = 0.f;
#pragma unroll
    for (int s = 0; s < RSEG; ++s) {
        mx = fmaxf(mx, pmax[(size_t)(b * RSEG + s) * NHID + f]);
        sm += psum[(size_t)(b * RSEG + s) * NHID + f];
    }
    a[f]       = accum[b * 256 + f] + mx;
    a[128 + f] = accum[b * 256 + 128 + f] + sm / (float)k;
    __syncthreads();
    float s = bl[f];
    for (int i = 0; i < 256; ++i) s = fmaf(a[i], Wl[i * NHID + f], s);
    out[b * NHID + f] = fmaxf(s, 0.f);
}

extern "C" void kernel_launch(void* const* d_in, const int* in_sizes, int n_in,
                              void* d_out, int out_size, void* d_ws, size_t ws_size,
                              hipStream_t stream) {
    const float* x0 = (const float*)d_in[0];
    const float* Wm[3] = {(const float*)d_in[1], (const float*)d_in[5], (const float*)d_in[9]};
    const float* bm[3] = {(const float*)d_in[2], (const float*)d_in[6], (const float*)d_in[10]};
    const float* Wsc[3] = {(const float*)d_in[3], (const float*)d_in[7], (const float*)d_in[11]};
    const float* bsc[3] = {(const float*)d_in[4], (const float*)d_in[8], (const float*)d_in[12]};
    const float* Wl = (const float*)d_in[13];
    const float* bl = (const float*)d_in[14];
    const int*   ei = (const int*)d_in[15];
    float* out = (float*)d_out;

    _Float16* bufA = (_Float16*)d_ws;                       // N0*128 halves (H)
    _Float16* bufB = bufA + (size_t)N0 * NHID;              // N0*128 (X)
    _Float16* WT1  = bufB + (size_t)N0 * NHID;              // 128*256
    _Float16* WT2  = WT1 + 128 * 256;                       // 128*128
    _Float16* WT3  = WT2 + 128 * 128;                       // 128*128
    float* hs     = (float*)(WT3 + 128 * 128);              // N0
    float* gate   = hs + N0;                                // N0
    float* accum  = gate + N0;                              // B*256
    float* pmax   = accum + B_GRAPHS * 256;                 // B*RSEG*128
    float* psum   = pmax + B_GRAPHS * RSEG * NHID;          // B*RSEG*128
    int*   cntA   = (int*)(psum + B_GRAPHS * RSEG * NHID);  // N0
    int*   cntB   = cntA + N0;                              // N0
    int*   offs   = cntB + N0;                              // N0
    int*   perm   = offs + N0;                              // N0
    int*   esrc   = perm + N0;                              // NE
    int*   edst   = esrc + NE;                              // NE
    float* ew     = (float*)(edst + NE);                    // NE
    int*   csr_src= (int*)(ew + NE);                        // NE
    float* csr_norm = (float*)(csr_src + NE);               // NE

    _Float16* WTs[3] = {WT1, WT2, WT3};
    const int EG = cdiv(NE, 256);

    k_fill_start<<<cdiv(N0, 256), 256, 0, stream>>>(cntA, accum);
    k_init_cvt<<<EG, 256, 0, stream>>>(ei, esrc, edst, ew, cntA,
                                       Wm[0], Wm[1], Wm[2], WT1, WT2, WT3);

    int npg = NPG0;
    _Float16* Hbuf = bufA; _Float16* Xbuf = bufB;

    for (int layer = 0; layer < 3; ++layer) {
        int N = B_GRAPHS * npg;
        int k = (npg * 4) / 5;   // ceil(0.8*n) exact for 2000/1600/1280
        int bpg = npg >> 2;      // blocks per graph in k_agg
        int* cnt  = (layer == 1) ? cntB : cntA;
        int* cntN = (layer == 1) ? cntA : cntB;

        if (layer == 0) {
            k_gemm_ws<1, 256, 0><<<cdiv(N, 64), 256, 0, stream>>>(x0, WTs[0], perm, gate, Hbuf, N);
            // layer-0 CSR comes from init edges; later layers build CSR inside scoretopk
            k_scancsr<<<B_GRAPHS, 1024, 0, stream>>>(cnt, offs, esrc, edst, ew,
                                                     csr_src, csr_norm, npg);
        } else {
            k_gemm_ws<0, 128, 1><<<cdiv(N, 64), 256, 0, stream>>>(Xbuf, WTs[layer], perm, gate, Hbuf, N);
        }
        k_agg<<<8 * GSLOTS * bpg, 256, 0, stream>>>(Hbuf, csr_src, csr_norm, offs, cnt,
                                                    bm[layer], Wsc[layer], Xbuf, hs, bpg, npg);
        if (layer == 0)
            k_scoretopk<1, 0><<<B_GRAPHS, 1024, 0, stream>>>(hs, csr_src, csr_norm, offs, cnt,
                                                             bsc[layer], perm, gate,
                                                             esrc, edst, ew, cntN,
                                                             pmax, psum, accum, npg, k);
        else if (layer == 1)
            k_scoretopk<1, 1><<<B_GRAPHS, 1024, 0, stream>>>(hs, csr_src, csr_norm, offs, cnt,
                                                             bsc[layer], perm, gate,
                                                             esrc, edst, ew, cntN,
                                                             pmax, psum, accum, npg, k);
        else
            k_scoretopk<0, 1><<<B_GRAPHS, 1024, 0, stream>>>(hs, csr_src, csr_norm, offs, cnt,
                                                             bsc[layer], perm, gate,
                                                             esrc, edst, ew, cntN,
                                                             pmax, psum, accum, npg, k);
        k_pool_readout<<<dim3(RSEG, B_GRAPHS), 128, 0, stream>>>(Xbuf, gate, perm, pmax, psum, k);
        if (layer == 2)
            k_comb_final<<<B_GRAPHS, 128, 0, stream>>>(pmax, psum, accum, Wl, bl, out, k);

        npg = k;
    }
}

// Round 12
// 543.382 us; speedup vs baseline: 1.0718x; 1.0114x over previous
//
#include <hip/hip_runtime.h>
#include <math.h>

#define B_GRAPHS 50
#define NPG0     2000
#define EPG      12000
#define F_IN_C   256
#define NHID     128
#define N0       (B_GRAPHS * NPG0)   // 100000
#define NE       (B_GRAPHS * EPG)    // 600000
#define RSEG     32                  // readout segments per graph (latency-bound gather)
#define GSLOTS   7                   // ceil(50 graphs / 8 XCDs)
#define CPAD     136
#define KMAX     1600                // max next-layer nodes per graph (layer-0 k)

typedef _Float16 f16x8 __attribute__((ext_vector_type(8)));
typedef float    f32x4 __attribute__((ext_vector_type(4)));

static inline int cdiv(int a, int b) { return (a + b - 1) / b; }

// ---------------- startup fill: zero cnt (N0) + accum ----------------
__global__ void k_fill_start(int* __restrict__ cnt, float* __restrict__ accum) {
    int i = blockIdx.x * 256 + threadIdx.x;
    if (i < N0) cnt[i] = 0;
    if (i < B_GRAPHS * 256) accum[i] = 0.f;
}

// ------- edge init + degree count (cnt pre-zeroed) + all weight transposes -------
__global__ void k_init_cvt(const int* __restrict__ ei, int* __restrict__ esrc,
                           int* __restrict__ edst, float* __restrict__ ew,
                           int* __restrict__ cnt,
                           const float* __restrict__ W1, const float* __restrict__ W2,
                           const float* __restrict__ W3, _Float16* __restrict__ WT1,
                           _Float16* __restrict__ WT2, _Float16* __restrict__ WT3) {
    int t = blockIdx.x * 256 + threadIdx.x;
    if (t < NE) {
        int d = ei[NE + t];
        esrc[t] = ei[t]; edst[t] = d; ew[t] = 1.0f;
        atomicAdd(&cnt[d], 1);
    }
    if (t < 128 * 256) {
        int n = t >> 8, kk = t & 255;
        WT1[t] = (_Float16)W1[kk * 128 + n];
    } else if (t < 128 * 256 + 128 * 128) {
        int u = t - 32768; int n = u >> 7, kk = u & 127;
        WT2[u] = (_Float16)W2[kk * 128 + n];
    } else if (t < 128 * 256 + 2 * 128 * 128) {
        int u = t - 49152; int n = u >> 7, kk = u & 127;
        WT3[u] = (_Float16)W3[kk * 128 + n];
    }
}

// ---------------- weight-stationary MFMA GEMM, 64-row M-tile (STANDALONE) ----------------
// Round-7 lesson: fusing helper roles into this kernel collapsed VGPR 100->60 and
// forced spills. Keep it single-role so the allocator serves the GEMM pipeline alone.
template<int FP32IN, int F, int GATHER>
__global__ __launch_bounds__(256) void k_gemm_ws(const void* __restrict__ Xin,
                                                 const _Float16* __restrict__ WT,
                                                 const int* __restrict__ perm,
                                                 const float* __restrict__ gate,
                                                 _Float16* __restrict__ H, int N) {
    constexpr int KH  = (F > 128) ? 128 : F;      // K-cols staged per phase (=128)
    constexpr int K8H = KH / 8;                   // f16x8 chunks per row per phase
    constexpr int SMEMSZ = (128 * KH > 64 * CPAD) ? 128 * KH : 64 * CPAD;
    __shared__ _Float16 smem[SMEMSZ];
    const int tid  = threadIdx.x;
    const int wave = tid >> 6, lane = tid & 63;
    const int quad = lane >> 4, l16 = lane & 15;
    const int m_blk = blockIdx.x * 64;

    f32x4 acc[8];
#pragma unroll
    for (int j = 0; j < 8; ++j) acc[j] = {0.f, 0.f, 0.f, 0.f};

    int row0 = m_blk + wave * 16 + l16;
    if (row0 > N - 1) row0 = N - 1;
    _Float16 g0 = (_Float16)1.0f;
    if (GATHER) {
        g0 = (_Float16)gate[row0];
        row0 = perm[row0];
    }
    const int sx = l16 & 7;
    constexpr int NKQ = F / 32;

    if (FP32IN) {
        constexpr int PD = (NKQ < 4) ? NKQ : 4;
        const float* base0 = (const float*)Xin + (size_t)row0 * F + quad * 8;
        float4 p0[PD][2];
        // A prologue first: HBM loads in flight while we stage W phase 0.
#pragma unroll
        for (int i = 0; i < PD; ++i) {
            p0[i][0] = ((const float4*)(base0 + i * 32))[0];
            p0[i][1] = ((const float4*)(base0 + i * 32))[1];
        }
        // stage W^T phase 0: columns k in [0, KH)
#pragma unroll
        for (int c = tid; c < 128 * K8H; c += 256) {
            int n = c / K8H, k8 = c - n * K8H;
            f16x8 v = *(const f16x8*)&WT[(size_t)(n * (F / 8) + k8) * 8];
            *(f16x8*)&smem[n * KH + ((k8 ^ (n & 7)) << 3)] = v;
        }
        __syncthreads();
#pragma unroll
        for (int kq = 0; kq < NKQ; ++kq) {
            if (KH < F && kq == NKQ / 2) {
                // phase flip: all waves done reading phase 0 -> restage phase 1
                __syncthreads();
#pragma unroll
                for (int c = tid; c < 128 * K8H; c += 256) {
                    int n = c / K8H, k8 = c - n * K8H;
                    f16x8 v = *(const f16x8*)&WT[(size_t)(n * (F / 8) + K8H + k8) * 8];
                    *(f16x8*)&smem[n * KH + ((k8 ^ (n & 7)) << 3)] = v;
                }
                __syncthreads();
            }
            const int b = kq % PD;
            float4 f0 = p0[b][0], f1 = p0[b][1];
            if (kq + PD < NKQ) {
                p0[b][0] = ((const float4*)(base0 + (kq + PD) * 32))[0];
                p0[b][1] = ((const float4*)(base0 + (kq + PD) * 32))[1];
            }
            f16x8 af0 = (f16x8){(_Float16)f0.x,(_Float16)f0.y,(_Float16)f0.z,(_Float16)f0.w,
                                (_Float16)f1.x,(_Float16)f1.y,(_Float16)f1.z,(_Float16)f1.w};
            f16x8 bf[8];
#pragma unroll
            for (int j = 0; j < 8; ++j)
                bf[j] = *(const f16x8*)&smem[(j * 16 + l16) * KH + (((((kq & 3) << 2) + quad) ^ sx) << 3)];
#pragma unroll
            for (int j = 0; j < 8; ++j)
                acc[j] = __builtin_amdgcn_mfma_f32_16x16x32_f16(af0, bf[j], acc[j], 0, 0, 0);
        }
    } else {
        // F=128: single stage, full prefetch — all NKQ loads issued before any MFMA
#pragma unroll
        for (int c = tid; c < 128 * K8H; c += 256) {
            int n = c / K8H, k8 = c - n * K8H;
            f16x8 v = *(const f16x8*)&WT[(size_t)(n * K8H + k8) * 8];
            *(f16x8*)&smem[n * KH + ((k8 ^ (n & 7)) << 3)] = v;
        }
        const _Float16* base0 = (const _Float16*)Xin + (size_t)row0 * F + quad * 8;
        f16x8 q0[NKQ];
#pragma unroll
        for (int i = 0; i < NKQ; ++i)
            q0[i] = *(const f16x8*)(base0 + i * 32);
        __syncthreads();
#pragma unroll
        for (int kq = 0; kq < NKQ; ++kq) {
            f16x8 af0 = q0[kq];
            if (GATHER) af0 = af0 * g0;
            f16x8 bf[8];
#pragma unroll
            for (int j = 0; j < 8; ++j)
                bf[j] = *(const f16x8*)&smem[(j * 16 + l16) * KH + (((((kq & 3) << 2) + quad) ^ sx) << 3)];
#pragma unroll
            for (int j = 0; j < 8; ++j)
                acc[j] = __builtin_amdgcn_mfma_f32_16x16x32_f16(af0, bf[j], acc[j], 0, 0, 0);
        }
    }
    __syncthreads();   // done reading W; reuse LDS for epilogue

    _Float16* sC = smem;                  // [64][CPAD]
    const int rw = wave * 16;
#pragma unroll
    for (int j = 0; j < 8; ++j)
#pragma unroll
        for (int g = 0; g < 4; ++g)
            sC[(rw + quad * 4 + g) * CPAD + j * 16 + l16] = (_Float16)acc[j][g];
    __syncthreads();
    {
        int rr = tid >> 2;                // 0..63
        int cc = (tid & 3) * 32;          // 0,32,64,96 halves
        int gr = m_blk + rr;
        if (gr < N) {
            _Float16* Hr = H + (size_t)gr * 128 + cc;
            const _Float16* Sr = sC + rr * CPAD + cc;
#pragma unroll
            for (int c = 0; c < 4; ++c)
                *(f16x8*)&Hr[c * 8] = *(const f16x8*)&Sr[c * 8];
        }
    }
}

// -------- per-graph CSR build for LAYER 0 only (scan + LDS-cursor edge fill) --------
__global__ __launch_bounds__(1024) void k_scancsr(const int* __restrict__ cnt,
                                                  int* __restrict__ offs,
                                                  const int* __restrict__ esrc,
                                                  const int* __restrict__ edst,
                                                  const float* __restrict__ ew,
                                                  int* __restrict__ csr_src,
                                                  float* __restrict__ csr_norm,
                                                  int npg) {
    __shared__ int ch[1024];
    __shared__ int scnt[2048];
    __shared__ int scur[2048];
    int b = blockIdx.x, tid = threadIdx.x;
    int base = b * npg;
    int per = (npg + 1023) >> 10;                 // =2 for npg<=2000
    int s0 = tid * per;
    int s1 = s0 + per; if (s1 > npg) s1 = npg; if (s0 > npg) s0 = npg;
    int s = 0;
    for (int i = s0; i < s1; ++i) { int c = cnt[base + i]; scnt[i] = c; s += c; }
    ch[tid] = s;
    __syncthreads();
    for (int d = 1; d < 1024; d <<= 1) {
        int t = ch[tid] + ((tid >= d) ? ch[tid - d] : 0);
        __syncthreads();
        ch[tid] = t;
        __syncthreads();
    }
    int run = b * EPG + ch[tid] - s;
    for (int i = s0; i < s1; ++i) {
        offs[base + i] = run; scur[i] = run;
        run += scnt[i];
    }
    __syncthreads();
    int e0 = b * EPG;
    for (int e = tid; e < EPG; e += 1024) {
        float w = ew[e0 + e];
        if (w > 0.f) {
            int sN = esrc[e0 + e], d = edst[e0 + e];
            int pos = atomicAdd(&scur[d - base], 1);
            csr_src[pos] = sN;
            csr_norm[pos] = rsqrtf((float)(scnt[sN - base] + 1)) *
                            rsqrtf((float)(scnt[d - base] + 1));
        }
    }
}

// -------- aggregation + fused score projection, 8-edge pipeline + XCD swizzle --------
__global__ __launch_bounds__(256) void k_agg(const _Float16* __restrict__ H,
                                             const int* __restrict__ csr_src,
                                             const float* __restrict__ csr_norm,
                                             const int* __restrict__ offs,
                                             const int* __restrict__ cnt,
                                             const float* __restrict__ bias,
                                             const float* __restrict__ Ws,
                                             _Float16* __restrict__ X,
                                             float* __restrict__ hs,
                                             int bpg, int npg) {
    int bi = blockIdx.x;
    int x = bi & 7, s = bi >> 3;
    int gslot = s / bpg, blk = s - gslot * bpg;
    int g = x + 8 * gslot;
    if (g >= B_GRAPHS) return;
    int node = g * npg + blk * 4 + (threadIdx.x >> 6);
    int lane = threadIdx.x & 63;
    int quad = lane >> 4, l16 = lane & 15;

    int st = offs[node], c = cnt[node], en = st + c;
    float acc[8];
#pragma unroll
    for (int j = 0; j < 8; ++j) acc[j] = 0.f;

    if (c > 0) {
        for (int e0 = st; e0 < en; e0 += 8) {
            int eA = e0 + quad, eB = eA + 4;
            int ecA = eA < en ? eA : en - 1;
            int ecB = eB < en ? eB : en - 1;
            int uA = csr_src[ecA], uB = csr_src[ecB];
            float nA = (eA < en) ? csr_norm[ecA] : 0.f;
            float nB = (eB < en) ? csr_norm[ecB] : 0.f;
            f16x8 hA = *(const f16x8*)&H[(size_t)uA * NHID + l16 * 8];
            f16x8 hB = *(const f16x8*)&H[(size_t)uB * NHID + l16 * 8];
#pragma unroll
            for (int j = 0; j < 8; ++j) acc[j] = fmaf((float)hA[j], nA, acc[j]);
#pragma unroll
            for (int j = 0; j < 8; ++j) acc[j] = fmaf((float)hB[j], nB, acc[j]);
        }
    }
#pragma unroll
    for (int j = 0; j < 8; ++j) {
        acc[j] += __shfl_xor(acc[j], 16, 64);
        acc[j] += __shfl_xor(acc[j], 32, 64);
    }
    float invd = 1.f / (float)(c + 1);
    f16x8 hn = *(const f16x8*)&H[(size_t)node * NHID + l16 * 8];
    float4 b0 = *(const float4*)&bias[l16 * 8];
    float4 b1 = *(const float4*)&bias[l16 * 8 + 4];
    float4 w0 = *(const float4*)&Ws[l16 * 8];
    float4 w1 = *(const float4*)&Ws[l16 * 8 + 4];
    const float bb[8] = {b0.x, b0.y, b0.z, b0.w, b1.x, b1.y, b1.z, b1.w};
    const float ww[8] = {w0.x, w0.y, w0.z, w0.w, w1.x, w1.y, w1.z, w1.w};
    float sd = 0.f;
    f16x8 o;
#pragma unroll
    for (int j = 0; j < 8; ++j) {
        float v = fmaxf(acc[j] + (float)hn[j] * invd + bb[j], 0.f);
        o[j] = (_Float16)v;
        sd = fmaf(v, ww[j], sd);
    }
    if (quad == 0)
        *(f16x8*)&X[(size_t)node * NHID + l16 * 8] = o;
    sd += __shfl_xor(sd, 1, 64);
    sd += __shfl_xor(sd, 2, 64);
    sd += __shfl_xor(sd, 4, 64);
    sd += __shfl_xor(sd, 8, 64);
    if (lane == 0) hs[node] = sd;
}

// --- fused: [COMB] + score + top-k (wave-resident bitonic) + remap + [REMAP: CSR] ---
// Bitonic: strides<=64 never cross a wave's 128-element span -> register-resident
// (shfl_xor for s<=32, in-lane lo/hi swap for s=64). Only strides>=128 (10 of 66
// iterations) touch LDS with barriers: 132 barriers -> ~16. Comparator identical
// (both pair-lanes evaluate the same (a,b)-ordered predicate; unique (score,idx)
// keys) -> bit-identical sort result vs the old LDS bitonic.
template<int REMAP, int COMB>
__global__ __launch_bounds__(1024) void k_scoretopk(const float* __restrict__ hs,
                                                    int* __restrict__ csr_src,
                                                    float* __restrict__ csr_norm,
                                                    int* __restrict__ offs,
                                                    const int* __restrict__ cnt,
                                                    const float* __restrict__ bs,
                                                    int* __restrict__ perm,
                                                    float* __restrict__ gate,
                                                    int* __restrict__ esrc,
                                                    int* __restrict__ edst,
                                                    float* __restrict__ ew,
                                                    int* __restrict__ cntN,
                                                    const float* __restrict__ pmax,
                                                    const float* __restrict__ psum,
                                                    float* __restrict__ accum,
                                                    int npg, int k) {
    __shared__ float ss[2048];
    __shared__ int   si[2048];
    __shared__ float shs[2048];               // hs cache; reused as smap (int) later
    __shared__ int   shist[KMAX];
    int b = blockIdx.x, tid = threadIdx.x;
    int base = b * npg;

    if (COMB) {
        // fold previous layer's readout partials into accum (block b owns graph b).
        if (tid < 2 * NHID) {
            int f = tid & 127;
            bool isSum = tid >= NHID;
            float a2 = isSum ? 0.f : -__builtin_inff();
            for (int s = 0; s < RSEG; ++s) {
                float v = (isSum ? psum : pmax)[(size_t)(b * RSEG + s) * NHID + f];
                a2 = isSum ? (a2 + v) : fmaxf(a2, v);
            }
            if (isSum) accum[b * 256 + 128 + f] += a2 / (float)npg;
            else       accum[b * 256 + f]       += a2;
        }
    }

    float bs0 = bs[0];
    for (int i = tid; i < 2048; i += 1024)
        shs[i] = (i < npg) ? hs[base + i] : 0.f;
    __syncthreads();
    for (int i = tid; i < 2048; i += 1024) {
        if (i < npg) {
            int st = offs[base + i], c = cnt[base + i];
            float a = 0.f;
            for (int e = st; e < st + c; ++e)
                a = fmaf(shs[csr_src[e] - base], csr_norm[e], a);
            ss[i] = a + shs[i] / (float)(c + 1) + bs0;
        } else {
            ss[i] = -__builtin_inff();
        }
        si[i] = i;
    }
    __syncthreads();

    // ---------------- wave-resident bitonic sort (desc score, asc idx) ----------------
    const int wbase = (tid >> 6) << 7;        // wave's 128-element base
    const int l = tid & 63;
    float vL = ss[wbase + l],      vH = ss[wbase + 64 + l];
    int   iL = si[wbase + l],      iH = si[wbase + 64 + l];

    auto reg_steps = [&](int size, int smax) {
        for (int s = smax; s > 0; s >>= 1) {
            if (s == 64) {
                bool fwd = (((wbase + l) & size) == 0);
                bool bba = (vH > vL) || (vH == vL && iH < iL);
                if (fwd ? bba : !bba) {
                    float tv = vL; vL = vH; vH = tv;
                    int ti = iL; iL = iH; iH = ti;
                }
            } else {
                bool iR = ((l & s) == 0);
                // lo element
                float pv = __shfl_xor(vL, s, 64);
                int   pi = __shfl_xor(iL, s, 64);
                float sa = iR ? vL : pv, sb = iR ? pv : vL;
                int   ia = iR ? iL : pi, ib = iR ? pi : iL;
                bool bba = (sb > sa) || (sb == sa && ib < ia);
                bool fwd = (((wbase + l) & size) == 0);
                if (fwd ? bba : !bba) { vL = pv; iL = pi; }
                // hi element
                pv = __shfl_xor(vH, s, 64);
                pi = __shfl_xor(iH, s, 64);
                sa = iR ? vH : pv; sb = iR ? pv : vH;
                ia = iR ? iH : pi; ib = iR ? pi : iH;
                bba = (sb > sa) || (sb == sa && ib < ia);
                bool fwd2 = (((wbase + 64 + l) & size) == 0);
                if (fwd2 ? bba : !bba) { vH = pv; iH = pi; }
            }
        }
    };

    // sizes 2..128: fully register-resident, zero barriers
    for (int size = 2; size <= 128; size <<= 1)
        reg_steps(size, size >> 1);
    // sizes 256..2048: strides >=128 in LDS, then strides <=64 in registers
    for (int size = 256; size <= 2048; size <<= 1) {
        ss[wbase + l] = vL;      si[wbase + l] = iL;
        ss[wbase + 64 + l] = vH; si[wbase + 64 + l] = iH;
        __syncthreads();
        for (int stride = size >> 1; stride >= 128; stride >>= 1) {
            int i = ((tid & ~(stride - 1)) << 1) | (tid & (stride - 1));
            int j = i | stride;
            float sa = ss[i], sb = ss[j];
            int   ia = si[i], ib = si[j];
            bool bba = (sb > sa) || (sb == sa && ib < ia);
            bool fwd = ((i & size) == 0);
            if (fwd ? bba : !bba) { ss[i] = sb; ss[j] = sa; si[i] = ib; si[j] = ia; }
            __syncthreads();
        }
        vL = ss[wbase + l];      iL = si[wbase + l];
        vH = ss[wbase + 64 + l]; iH = si[wbase + 64 + l];
        reg_steps(size, 64);
    }
    ss[wbase + l] = vL;      si[wbase + l] = iL;
    ss[wbase + 64 + l] = vH; si[wbase + 64 + l] = iH;
    __syncthreads();

    int* smap = (int*)shs;                    // safe: shs dead after score phase
    for (int j = tid; j < npg; j += 1024) {
        int ol = si[j];
        if (j < k) {
            int newg = b * k + j;
            perm[newg] = base + ol;
            smap[ol] = newg;
            gate[newg] = tanhf(ss[j]);
        } else {
            smap[ol] = -1;
        }
    }
    if (REMAP) {
        for (int j = tid; j < k; j += 1024) shist[j] = 0;
        __syncthreads();                      // also fences output-phase ss/si reads
        int e0 = b * EPG;
        for (int e = tid; e < EPG; e += 1024) {
            int idx = e0 + e;
            float w = ew[idx];
            bool valid = false;
            int ns = 0, nd = 0;
            if (w > 0.f) {                    // guard BEFORE map lookup
                ns = smap[esrc[idx] - base];
                nd = smap[edst[idx] - base];
                valid = (ns >= 0) && (nd >= 0);
            }
            esrc[idx] = valid ? ns : 0;
            edst[idx] = valid ? nd : 0;
            ew[idx]   = valid ? w : 0.f;
            if (valid) atomicAdd(&shist[nd - b * k], 1);
        }
        __syncthreads();                      // shist final; ss/si free for reuse
        // ---- next-layer CSR build: prefix-scan shist -> offs/cursors, then fill ----
        int* sscan = (int*)ss;                // scan scratch
        int* scur  = si;                      // per-node cursors
        int per2 = (k + 1023) >> 10;          // =2 for k<=1600
        int t0 = tid * per2, t1 = t0 + per2;
        if (t1 > k) t1 = k; if (t0 > k) t0 = k;
        int sloc = 0;
        for (int i = t0; i < t1; ++i) sloc += shist[i];
        sscan[tid] = sloc;
        __syncthreads();
        for (int d = 1; d < 1024; d <<= 1) {
            int t = sscan[tid] + ((tid >= d) ? sscan[tid - d] : 0);
            __syncthreads();
            sscan[tid] = t;
            __syncthreads();
        }
        int run = b * EPG + sscan[tid] - sloc;
        for (int i = t0; i < t1; ++i) {
            offs[b * k + i] = run; scur[i] = run;
            cntN[b * k + i] = shist[i];
            run += shist[i];
        }
        __syncthreads();
        // fill pass: re-read remapped edges (block-local, L2-hot), LDS cursor atomics
        for (int e = tid; e < EPG; e += 1024) {
            int idx = e0 + e;
            float w = ew[idx];
            if (w > 0.f) {
                int ns = esrc[idx], nd = edst[idx];
                int pos = atomicAdd(&scur[nd - b * k], 1);
                csr_src[pos] = ns;
                csr_norm[pos] = rsqrtf((float)(shist[ns - b * k] + 1)) *
                                rsqrtf((float)(shist[nd - b * k] + 1));
            }
        }
    }
}

// ---------------- partial readout over pooled rows (no XP materialization) ----------------
__global__ __launch_bounds__(128) void k_pool_readout(const _Float16* __restrict__ X,
                                                      const float* __restrict__ gate,
                                                      const int* __restrict__ perm,
                                                      float* __restrict__ pmax,
                                                      float* __restrict__ psum, int k) {
    int s = blockIdx.x, b = blockIdx.y, f = threadIdx.x;
    int j0 = (k * s) / RSEG, j1 = (k * (s + 1)) / RSEG;
    float mx = -__builtin_inff(), sm = 0.f;
    for (int j = j0; j < j1; ++j) {
        int g = b * k + j;
        int old = perm[g];
        float v = (float)X[(size_t)old * NHID + f] * gate[g];
        mx = fmaxf(mx, v);
        sm += v;
    }
    pmax[(size_t)(b * RSEG + s) * NHID + f] = mx;
    psum[(size_t)(b * RSEG + s) * NHID + f] = sm;
}

// ---------------- fused layer-3 readout-combine + final linear ----------------
__global__ __launch_bounds__(128) void k_comb_final(const float* __restrict__ pmax,
                                                    const float* __restrict__ psum,
                                                    const float* __restrict__ accum,
                                                    const float* __restrict__ Wl,
                                                    const float* __restrict__ bl,
                                                    float* __restrict__ out, int k) {
    __shared__ float a[256];
    int b = blockIdx.x, f = threadIdx.x;
    float mx = -__builtin_inff(), sm = 0.f;
#pragma unroll
    for (int s = 0; s < RSEG; ++s) {
        mx = fmaxf(mx, pmax[(size_t)(b * RSEG + s) * NHID + f]);
        sm += psum[(size_t)(b * RSEG + s) * NHID + f];
    }
    a[f]       = accum[b * 256 + f] + mx;
    a[128 + f] = accum[b * 256 + 128 + f] + sm / (float)k;
    __syncthreads();
    float s = bl[f];
    for (int i = 0; i < 256; ++i) s = fmaf(a[i], Wl[i * NHID + f], s);
    out[b * NHID + f] = fmaxf(s, 0.f);
}

extern "C" void kernel_launch(void* const* d_in, const int* in_sizes, int n_in,
                              void* d_out, int out_size, void* d_ws, size_t ws_size,
                              hipStream_t stream) {
    const float* x0 = (const float*)d_in[0];
    const float* Wm[3] = {(const float*)d_in[1], (const float*)d_in[5], (const float*)d_in[9]};
    const float* bm[3] = {(const float*)d_in[2], (const float*)d_in[6], (const float*)d_in[10]};
    const float* Wsc[3] = {(const float*)d_in[3], (const float*)d_in[7], (const float*)d_in[11]};
    const float* bsc[3] = {(const float*)d_in[4], (const float*)d_in[8], (const float*)d_in[12]};
    const float* Wl = (const float*)d_in[13];
    const float* bl = (const float*)d_in[14];
    const int*   ei = (const int*)d_in[15];
    float* out = (float*)d_out;

    _Float16* bufA = (_Float16*)d_ws;                       // N0*128 halves (H)
    _Float16* bufB = bufA + (size_t)N0 * NHID;              // N0*128 (X)
    _Float16* WT1  = bufB + (size_t)N0 * NHID;              // 128*256
    _Float16* WT2  = WT1 + 128 * 256;                       // 128*128
    _Float16* WT3  = WT2 + 128 * 128;                       // 128*128
    float* hs     = (float*)(WT3 + 128 * 128);              // N0
    float* gate   = hs + N0;                                // N0
    float* accum  = gate + N0;                              // B*256
    float* pmax   = accum + B_GRAPHS * 256;                 // B*RSEG*128
    float* psum   = pmax + B_GRAPHS * RSEG * NHID;          // B*RSEG*128
    int*   cntA   = (int*)(psum + B_GRAPHS * RSEG * NHID);  // N0
    int*   cntB   = cntA + N0;                              // N0
    int*   offs   = cntB + N0;                              // N0
    int*   perm   = offs + N0;                              // N0
    int*   esrc   = perm + N0;                              // NE
    int*   edst   = esrc + NE;                              // NE
    float* ew     = (float*)(edst + NE);                    // NE
    int*   csr_src= (int*)(ew + NE);                        // NE
    float* csr_norm = (float*)(csr_src + NE);               // NE

    _Float16* WTs[3] = {WT1, WT2, WT3};
    const int EG = cdiv(NE, 256);

    k_fill_start<<<cdiv(N0, 256), 256, 0, stream>>>(cntA, accum);
    k_init_cvt<<<EG, 256, 0, stream>>>(ei, esrc, edst, ew, cntA,
                                       Wm[0], Wm[1], Wm[2], WT1, WT2, WT3);

    int npg = NPG0;
    _Float16* Hbuf = bufA; _Float16* Xbuf = bufB;

    for (int layer = 0; layer < 3; ++layer) {
        int N = B_GRAPHS * npg;
        int k = (npg * 4) / 5;   // ceil(0.8*n) exact for 2000/1600/1280
        int bpg = npg >> 2;      // blocks per graph in k_agg
        int* cnt  = (layer == 1) ? cntB : cntA;
        int* cntN = (layer == 1) ? cntA : cntB;

        if (layer == 0) {
            k_gemm_ws<1, 256, 0><<<cdiv(N, 64), 256, 0, stream>>>(x0, WTs[0], perm, gate, Hbuf, N);
            // layer-0 CSR comes from init edges; later layers build CSR inside scoretopk
            k_scancsr<<<B_GRAPHS, 1024, 0, stream>>>(cnt, offs, esrc, edst, ew,
                                                     csr_src, csr_norm, npg);
        } else {
            k_gemm_ws<0, 128, 1><<<cdiv(N, 64), 256, 0, stream>>>(Xbuf, WTs[layer], perm, gate, Hbuf, N);
        }
        k_agg<<<8 * GSLOTS * bpg, 256, 0, stream>>>(Hbuf, csr_src, csr_norm, offs, cnt,
                                                    bm[layer], Wsc[layer], Xbuf, hs, bpg, npg);
        if (layer == 0)
            k_scoretopk<1, 0><<<B_GRAPHS, 1024, 0, stream>>>(hs, csr_src, csr_norm, offs, cnt,
                                                             bsc[layer], perm, gate,
                                                             esrc, edst, ew, cntN,
                                                             pmax, psum, accum, npg, k);
        else if (layer == 1)
            k_scoretopk<1, 1><<<B_GRAPHS, 1024, 0, stream>>>(hs, csr_src, csr_norm, offs, cnt,
                                                             bsc[layer], perm, gate,
                                                             esrc, edst, ew, cntN,
                                                             pmax, psum, accum, npg, k);
        else
            k_scoretopk<0, 1><<<B_GRAPHS, 1024, 0, stream>>>(hs, csr_src, csr_norm, offs, cnt,
                                                             bsc[layer], perm, gate,
                                                             esrc, edst, ew, cntN,
                                                             pmax, psum, accum, npg, k);
        k_pool_readout<<<dim3(RSEG, B_GRAPHS), 128, 0, stream>>>(Xbuf, gate, perm, pmax, psum, k);
        if (layer == 2)
            k_comb_final<<<B_GRAPHS, 128, 0, stream>>>(pmax, psum, accum, Wl, bl, out, k);

        npg = k;
    }
}

// Round 14
// 539.188 us; speedup vs baseline: 1.0801x; 1.0078x over previous
//
#include <hip/hip_runtime.h>
#include <math.h>

#define B_GRAPHS 50
#define NPG0     2000
#define EPG      12000
#define F_IN_C   256
#define NHID     128
#define N0       (B_GRAPHS * NPG0)   // 100000
#define NE       (B_GRAPHS * EPG)    // 600000
#define RSEG     32                  // readout segments per graph (layer-2 standalone pool)
#define GSLOTS   7                   // ceil(50 graphs / 8 XCDs)
#define CPAD     136
#define KMAX     1600                // max next-layer nodes per graph (layer-0 k)

typedef _Float16 f16x8 __attribute__((ext_vector_type(8)));
typedef float    f32x4 __attribute__((ext_vector_type(4)));

static inline int cdiv(int a, int b) { return (a + b - 1) / b; }

// ---------------- startup fill: zero cnt (N0) + accum ----------------
__global__ void k_fill_start(int* __restrict__ cnt, float* __restrict__ accum) {
    int i = blockIdx.x * 256 + threadIdx.x;
    if (i < N0) cnt[i] = 0;
    if (i < B_GRAPHS * 256) accum[i] = 0.f;
}

// ------- edge init + degree count (cnt pre-zeroed) + all weight transposes -------
__global__ void k_init_cvt(const int* __restrict__ ei, int* __restrict__ esrc,
                           int* __restrict__ edst, float* __restrict__ ew,
                           int* __restrict__ cnt,
                           const float* __restrict__ W1, const float* __restrict__ W2,
                           const float* __restrict__ W3, _Float16* __restrict__ WT1,
                           _Float16* __restrict__ WT2, _Float16* __restrict__ WT3) {
    int t = blockIdx.x * 256 + threadIdx.x;
    if (t < NE) {
        int d = ei[NE + t];
        esrc[t] = ei[t]; edst[t] = d; ew[t] = 1.0f;
        atomicAdd(&cnt[d], 1);
    }
    if (t < 128 * 256) {
        int n = t >> 8, kk = t & 255;
        WT1[t] = (_Float16)W1[kk * 128 + n];
    } else if (t < 128 * 256 + 128 * 128) {
        int u = t - 32768; int n = u >> 7, kk = u & 127;
        WT2[u] = (_Float16)W2[kk * 128 + n];
    } else if (t < 128 * 256 + 2 * 128 * 128) {
        int u = t - 49152; int n = u >> 7, kk = u & 127;
        WT3[u] = (_Float16)W3[kk * 128 + n];
    }
}

// ---------------- weight-stationary MFMA GEMM, 64-row M-tile (STANDALONE) ----------------
// Round-7 lesson: separate-role fat blocks force allocator compromise -> spills. POOL here
// is NOT a separate role: it reuses the gather rows already in this wave's registers (q0)
// to emit the PREVIOUS layer's readout partials (per-block, no atomics; blocks never
// straddle graphs since k % 64 == 0). Eliminates standalone k_pool_readout for L0/L1.
template<int FP32IN, int F, int GATHER, int POOL>
__global__ __launch_bounds__(256) void k_gemm_ws(const void* __restrict__ Xin,
                                                 const _Float16* __restrict__ WT,
                                                 const int* __restrict__ perm,
                                                 const float* __restrict__ gate,
                                                 _Float16* __restrict__ H, int N,
                                                 float* __restrict__ pmax,
                                                 float* __restrict__ psum) {
    constexpr int KH  = (F > 128) ? 128 : F;      // K-cols staged per phase (=128)
    constexpr int K8H = KH / 8;                   // f16x8 chunks per row per phase
    constexpr int SMEMSZ = (128 * KH > 64 * CPAD) ? 128 * KH : 64 * CPAD;
    __shared__ _Float16 smem[SMEMSZ];
    const int tid  = threadIdx.x;
    const int wave = tid >> 6, lane = tid & 63;
    const int quad = lane >> 4, l16 = lane & 15;
    const int m_blk = blockIdx.x * 64;

    f32x4 acc[8];
#pragma unroll
    for (int j = 0; j < 8; ++j) acc[j] = {0.f, 0.f, 0.f, 0.f};

    int row0 = m_blk + wave * 16 + l16;
    if (row0 > N - 1) row0 = N - 1;
    _Float16 g0 = (_Float16)1.0f;
    float g0f = 1.0f;
    if (GATHER) {
        g0f = gate[row0];
        g0 = (_Float16)g0f;
        row0 = perm[row0];
    }
    const int sx = l16 & 7;
    constexpr int NKQ = F / 32;

    f16x8 q0[NKQ];                                // F=128 row cache (reused by POOL)

    if (FP32IN) {
        constexpr int PD = (NKQ < 4) ? NKQ : 4;
        const float* base0 = (const float*)Xin + (size_t)row0 * F + quad * 8;
        float4 p0[PD][2];
        // A prologue first: HBM loads in flight while we stage W phase 0.
#pragma unroll
        for (int i = 0; i < PD; ++i) {
            p0[i][0] = ((const float4*)(base0 + i * 32))[0];
            p0[i][1] = ((const float4*)(base0 + i * 32))[1];
        }
        // stage W^T phase 0: columns k in [0, KH)
#pragma unroll
        for (int c = tid; c < 128 * K8H; c += 256) {
            int n = c / K8H, k8 = c - n * K8H;
            f16x8 v = *(const f16x8*)&WT[(size_t)(n * (F / 8) + k8) * 8];
            *(f16x8*)&smem[n * KH + ((k8 ^ (n & 7)) << 3)] = v;
        }
        __syncthreads();
#pragma unroll
        for (int kq = 0; kq < NKQ; ++kq) {
            if (KH < F && kq == NKQ / 2) {
                // phase flip: all waves done reading phase 0 -> restage phase 1
                __syncthreads();
#pragma unroll
                for (int c = tid; c < 128 * K8H; c += 256) {
                    int n = c / K8H, k8 = c - n * K8H;
                    f16x8 v = *(const f16x8*)&WT[(size_t)(n * (F / 8) + K8H + k8) * 8];
                    *(f16x8*)&smem[n * KH + ((k8 ^ (n & 7)) << 3)] = v;
                }
                __syncthreads();
            }
            const int b = kq % PD;
            float4 f0 = p0[b][0], f1 = p0[b][1];
            if (kq + PD < NKQ) {
                p0[b][0] = ((const float4*)(base0 + (kq + PD) * 32))[0];
                p0[b][1] = ((const float4*)(base0 + (kq + PD) * 32))[1];
            }
            f16x8 af0 = (f16x8){(_Float16)f0.x,(_Float16)f0.y,(_Float16)f0.z,(_Float16)f0.w,
                                (_Float16)f1.x,(_Float16)f1.y,(_Float16)f1.z,(_Float16)f1.w};
            f16x8 bf[8];
#pragma unroll
            for (int j = 0; j < 8; ++j)
                bf[j] = *(const f16x8*)&smem[(j * 16 + l16) * KH + (((((kq & 3) << 2) + quad) ^ sx) << 3)];
#pragma unroll
            for (int j = 0; j < 8; ++j)
                acc[j] = __builtin_amdgcn_mfma_f32_16x16x32_f16(af0, bf[j], acc[j], 0, 0, 0);
        }
    } else {
        // F=128: single stage, full prefetch — all NKQ loads issued before any MFMA
#pragma unroll
        for (int c = tid; c < 128 * K8H; c += 256) {
            int n = c / K8H, k8 = c - n * K8H;
            f16x8 v = *(const f16x8*)&WT[(size_t)(n * K8H + k8) * 8];
            *(f16x8*)&smem[n * KH + ((k8 ^ (n & 7)) << 3)] = v;
        }
        const _Float16* base0 = (const _Float16*)Xin + (size_t)row0 * F + quad * 8;
#pragma unroll
        for (int i = 0; i < NKQ; ++i)
            q0[i] = *(const f16x8*)(base0 + i * 32);
        __syncthreads();
#pragma unroll
        for (int kq = 0; kq < NKQ; ++kq) {
            f16x8 af0 = q0[kq];
            if (GATHER) af0 = af0 * g0;
            f16x8 bf[8];
#pragma unroll
            for (int j = 0; j < 8; ++j)
                bf[j] = *(const f16x8*)&smem[(j * 16 + l16) * KH + (((((kq & 3) << 2) + quad) ^ sx) << 3)];
#pragma unroll
            for (int j = 0; j < 8; ++j)
                acc[j] = __builtin_amdgcn_mfma_f32_16x16x32_f16(af0, bf[j], acc[j], 0, 0, 0);
        }
    }
    __syncthreads();   // done reading W; reuse LDS for epilogue

    _Float16* sC = smem;                  // [64][CPAD]
    const int rw = wave * 16;
#pragma unroll
    for (int j = 0; j < 8; ++j)
#pragma unroll
        for (int g = 0; g < 4; ++g)
            sC[(rw + quad * 4 + g) * CPAD + j * 16 + l16] = (_Float16)acc[j][g];
    __syncthreads();
    {
        int rr = tid >> 2;                // 0..63
        int cc = (tid & 3) * 32;          // 0,32,64,96 halves
        int gr = m_blk + rr;
        if (gr < N) {
            _Float16* Hr = H + (size_t)gr * 128 + cc;
            const _Float16* Sr = sC + rr * CPAD + cc;
#pragma unroll
            for (int c = 0; c < 4; ++c)
                *(f16x8*)&Hr[c * 8] = *(const f16x8*)&Sr[c * 8];
        }
    }
    if (POOL && GATHER && !FP32IN) {
        // ---- previous layer's readout partials from resident gather rows ----
        // v = (float)X[perm[r]][f] * gate[r] in fp32 (same multiply as standalone pool).
        __syncthreads();                  // sC reads done; reuse smem
        float* smax = (float*)smem;       // [4][128]
        float* ssum = smax + 4 * 128;     // [4][128]
#pragma unroll
        for (int kq = 0; kq < NKQ; ++kq) {
#pragma unroll
            for (int j = 0; j < 8; ++j) {
                float v = (float)q0[kq][j] * g0f;
                float mx = v, sm = v;
#pragma unroll
                for (int s2 = 1; s2 < 16; s2 <<= 1) {
                    mx = fmaxf(mx, __shfl_xor(mx, s2, 64));
                    sm += __shfl_xor(sm, s2, 64);
                }
                if (l16 == 0) {
                    int f = kq * 32 + quad * 8 + j;
                    smax[wave * 128 + f] = mx;
                    ssum[wave * 128 + f] = sm;
                }
            }
        }
        __syncthreads();
        if (tid < 128) {
            float mx = fmaxf(fmaxf(smax[tid], smax[128 + tid]),
                             fmaxf(smax[256 + tid], smax[384 + tid]));
            float sm = ssum[tid] + ssum[128 + tid] + ssum[256 + tid] + ssum[384 + tid];
            int kprev = N / B_GRAPHS;     // rows per graph (divisible by 64)
            int g = m_blk / kprev;
            int blkg = (m_blk - g * kprev) >> 6;
            pmax[(size_t)(g * RSEG + blkg) * NHID + tid] = mx;
            psum[(size_t)(g * RSEG + blkg) * NHID + tid] = sm;
        }
    }
}

// -------- per-graph CSR build for LAYER 0 only (scan + LDS-cursor edge fill) --------
__global__ __launch_bounds__(1024) void k_scancsr(const int* __restrict__ cnt,
                                                  int* __restrict__ offs,
                                                  const int* __restrict__ esrc,
                                                  const int* __restrict__ edst,
                                                  const float* __restrict__ ew,
                                                  int* __restrict__ csr_src,
                                                  float* __restrict__ csr_norm,
                                                  int npg) {
    __shared__ int ch[1024];
    __shared__ int scnt[2048];
    __shared__ int scur[2048];
    int b = blockIdx.x, tid = threadIdx.x;
    int base = b * npg;
    int per = (npg + 1023) >> 10;                 // =2 for npg<=2000
    int s0 = tid * per;
    int s1 = s0 + per; if (s1 > npg) s1 = npg; if (s0 > npg) s0 = npg;
    int s = 0;
    for (int i = s0; i < s1; ++i) { int c = cnt[base + i]; scnt[i] = c; s += c; }
    ch[tid] = s;
    __syncthreads();
    for (int d = 1; d < 1024; d <<= 1) {
        int t = ch[tid] + ((tid >= d) ? ch[tid - d] : 0);
        __syncthreads();
        ch[tid] = t;
        __syncthreads();
    }
    int run = b * EPG + ch[tid] - s;
    for (int i = s0; i < s1; ++i) {
        offs[base + i] = run; scur[i] = run;
        run += scnt[i];
    }
    __syncthreads();
    int e0 = b * EPG;
    for (int e = tid; e < EPG; e += 1024) {
        float w = ew[e0 + e];
        if (w > 0.f) {
            int sN = esrc[e0 + e], d = edst[e0 + e];
            int pos = atomicAdd(&scur[d - base], 1);
            csr_src[pos] = sN;
            csr_norm[pos] = rsqrtf((float)(scnt[sN - base] + 1)) *
                            rsqrtf((float)(scnt[d - base] + 1));
        }
    }
}

// -------- aggregation + fused score projection, 8-edge pipeline + XCD swizzle --------
__global__ __launch_bounds__(256) void k_agg(const _Float16* __restrict__ H,
                                             const int* __restrict__ csr_src,
                                             const float* __restrict__ csr_norm,
                                             const int* __restrict__ offs,
                                             const int* __restrict__ cnt,
                                             const float* __restrict__ bias,
                                             const float* __restrict__ Ws,
                                             _Float16* __restrict__ X,
                                             float* __restrict__ hs,
                                             int bpg, int npg) {
    int bi = blockIdx.x;
    int x = bi & 7, s = bi >> 3;
    int gslot = s / bpg, blk = s - gslot * bpg;
    int g = x + 8 * gslot;
    if (g >= B_GRAPHS) return;
    int node = g * npg + blk * 4 + (threadIdx.x >> 6);
    int lane = threadIdx.x & 63;
    int quad = lane >> 4, l16 = lane & 15;

    int st = offs[node], c = cnt[node], en = st + c;
    float acc[8];
#pragma unroll
    for (int j = 0; j < 8; ++j) acc[j] = 0.f;

    if (c > 0) {
        for (int e0 = st; e0 < en; e0 += 8) {
            int eA = e0 + quad, eB = eA + 4;
            int ecA = eA < en ? eA : en - 1;
            int ecB = eB < en ? eB : en - 1;
            int uA = csr_src[ecA], uB = csr_src[ecB];
            float nA = (eA < en) ? csr_norm[ecA] : 0.f;
            float nB = (eB < en) ? csr_norm[ecB] : 0.f;
            f16x8 hA = *(const f16x8*)&H[(size_t)uA * NHID + l16 * 8];
            f16x8 hB = *(const f16x8*)&H[(size_t)uB * NHID + l16 * 8];
#pragma unroll
            for (int j = 0; j < 8; ++j) acc[j] = fmaf((float)hA[j], nA, acc[j]);
#pragma unroll
            for (int j = 0; j < 8; ++j) acc[j] = fmaf((float)hB[j], nB, acc[j]);
        }
    }
#pragma unroll
    for (int j = 0; j < 8; ++j) {
        acc[j] += __shfl_xor(acc[j], 16, 64);
        acc[j] += __shfl_xor(acc[j], 32, 64);
    }
    float invd = 1.f / (float)(c + 1);
    f16x8 hn = *(const f16x8*)&H[(size_t)node * NHID + l16 * 8];
    float4 b0 = *(const float4*)&bias[l16 * 8];
    float4 b1 = *(const float4*)&bias[l16 * 8 + 4];
    float4 w0 = *(const float4*)&Ws[l16 * 8];
    float4 w1 = *(const float4*)&Ws[l16 * 8 + 4];
    const float bb[8] = {b0.x, b0.y, b0.z, b0.w, b1.x, b1.y, b1.z, b1.w};
    const float ww[8] = {w0.x, w0.y, w0.z, w0.w, w1.x, w1.y, w1.z, w1.w};
    float sd = 0.f;
    f16x8 o;
#pragma unroll
    for (int j = 0; j < 8; ++j) {
        float v = fmaxf(acc[j] + (float)hn[j] * invd + bb[j], 0.f);
        o[j] = (_Float16)v;
        sd = fmaf(v, ww[j], sd);
    }
    if (quad == 0)
        *(f16x8*)&X[(size_t)node * NHID + l16 * 8] = o;
    sd += __shfl_xor(sd, 1, 64);
    sd += __shfl_xor(sd, 2, 64);
    sd += __shfl_xor(sd, 4, 64);
    sd += __shfl_xor(sd, 8, 64);
    if (lane == 0) hs[node] = sd;
}

// --- fused: [COMB: fold prev-layer pool partials (nseg slots)] + score
//     + top-k (wave-resident bitonic) + remap + [REMAP: next-layer CSR build] ---
template<int REMAP, int COMB>
__global__ __launch_bounds__(1024) void k_scoretopk(const float* __restrict__ hs,
                                                    int* __restrict__ csr_src,
                                                    float* __restrict__ csr_norm,
                                                    int* __restrict__ offs,
                                                    const int* __restrict__ cnt,
                                                    const float* __restrict__ bs,
                                                    int* __restrict__ perm,
                                                    float* __restrict__ gate,
                                                    int* __restrict__ esrc,
                                                    int* __restrict__ edst,
                                                    float* __restrict__ ew,
                                                    int* __restrict__ cntN,
                                                    const float* __restrict__ pmax,
                                                    const float* __restrict__ psum,
                                                    float* __restrict__ accum,
                                                    int npg, int k, int nseg) {
    __shared__ float ss[2048];
    __shared__ int   si[2048];
    __shared__ float shs[2048];               // hs cache; reused as smap (int) later
    __shared__ int   shist[KMAX];
    int b = blockIdx.x, tid = threadIdx.x;
    int base = b * npg;

    if (COMB) {
        // fold previous layer's pool partials into accum (block b owns graph b).
        if (tid < 2 * NHID) {
            int f = tid & 127;
            bool isSum = tid >= NHID;
            float a2 = isSum ? 0.f : -__builtin_inff();
            for (int s = 0; s < nseg; ++s) {
                float v = (isSum ? psum : pmax)[(size_t)(b * RSEG + s) * NHID + f];
                a2 = isSum ? (a2 + v) : fmaxf(a2, v);
            }
            if (isSum) accum[b * 256 + 128 + f] += a2 / (float)npg;
            else       accum[b * 256 + f]       += a2;
        }
    }

    float bs0 = bs[0];
    for (int i = tid; i < 2048; i += 1024)
        shs[i] = (i < npg) ? hs[base + i] : 0.f;
    __syncthreads();
    for (int i = tid; i < 2048; i += 1024) {
        if (i < npg) {
            int st = offs[base + i], c = cnt[base + i];
            float a = 0.f;
            for (int e = st; e < st + c; ++e)
                a = fmaf(shs[csr_src[e] - base], csr_norm[e], a);
            ss[i] = a + shs[i] / (float)(c + 1) + bs0;
        } else {
            ss[i] = -__builtin_inff();
        }
        si[i] = i;
    }
    __syncthreads();

    // ---------------- wave-resident bitonic sort (desc score, asc idx) ----------------
    const int wbase = (tid >> 6) << 7;        // wave's 128-element base
    const int l = tid & 63;
    float vL = ss[wbase + l],      vH = ss[wbase + 64 + l];
    int   iL = si[wbase + l],      iH = si[wbase + 64 + l];

    auto reg_steps = [&](int size, int smax) {
        for (int s = smax; s > 0; s >>= 1) {
            if (s == 64) {
                bool fwd = (((wbase + l) & size) == 0);
                bool bba = (vH > vL) || (vH == vL && iH < iL);
                if (fwd ? bba : !bba) {
                    float tv = vL; vL = vH; vH = tv;
                    int ti = iL; iL = iH; iH = ti;
                }
            } else {
                bool iR = ((l & s) == 0);
                float pv = __shfl_xor(vL, s, 64);
                int   pi = __shfl_xor(iL, s, 64);
                float sa = iR ? vL : pv, sb = iR ? pv : vL;
                int   ia = iR ? iL : pi, ib = iR ? pi : iL;
                bool bba = (sb > sa) || (sb == sa && ib < ia);
                bool fwd = (((wbase + l) & size) == 0);
                if (fwd ? bba : !bba) { vL = pv; iL = pi; }
                pv = __shfl_xor(vH, s, 64);
                pi = __shfl_xor(iH, s, 64);
                sa = iR ? vH : pv; sb = iR ? pv : vH;
                ia = iR ? iH : pi; ib = iR ? pi : iH;
                bba = (sb > sa) || (sb == sa && ib < ia);
                bool fwd2 = (((wbase + 64 + l) & size) == 0);
                if (fwd2 ? bba : !bba) { vH = pv; iH = pi; }
            }
        }
    };

    for (int size = 2; size <= 128; size <<= 1)
        reg_steps(size, size >> 1);
    for (int size = 256; size <= 2048; size <<= 1) {
        ss[wbase + l] = vL;      si[wbase + l] = iL;
        ss[wbase + 64 + l] = vH; si[wbase + 64 + l] = iH;
        __syncthreads();
        for (int stride = size >> 1; stride >= 128; stride >>= 1) {
            int i = ((tid & ~(stride - 1)) << 1) | (tid & (stride - 1));
            int j = i | stride;
            float sa = ss[i], sb = ss[j];
            int   ia = si[i], ib = si[j];
            bool bba = (sb > sa) || (sb == sa && ib < ia);
            bool fwd = ((i & size) == 0);
            if (fwd ? bba : !bba) { ss[i] = sb; ss[j] = sa; si[i] = ib; si[j] = ia; }
            __syncthreads();
        }
        vL = ss[wbase + l];      iL = si[wbase + l];
        vH = ss[wbase + 64 + l]; iH = si[wbase + 64 + l];
        reg_steps(size, 64);
    }
    ss[wbase + l] = vL;      si[wbase + l] = iL;
    ss[wbase + 64 + l] = vH; si[wbase + 64 + l] = iH;
    __syncthreads();

    int* smap = (int*)shs;                    // safe: shs dead after score phase
    for (int j = tid; j < npg; j += 1024) {
        int ol = si[j];
        if (j < k) {
            int newg = b * k + j;
            perm[newg] = base + ol;
            smap[ol] = newg;
            gate[newg] = tanhf(ss[j]);
        } else {
            smap[ol] = -1;
        }
    }
    if (REMAP) {
        for (int j = tid; j < k; j += 1024) shist[j] = 0;
        __syncthreads();                      // also fences output-phase ss/si reads
        int e0 = b * EPG;
        for (int e = tid; e < EPG; e += 1024) {
            int idx = e0 + e;
            float w = ew[idx];
            bool valid = false;
            int ns = 0, nd = 0;
            if (w > 0.f) {                    // guard BEFORE map lookup
                ns = smap[esrc[idx] - base];
                nd = smap[edst[idx] - base];
                valid = (ns >= 0) && (nd >= 0);
            }
            esrc[idx] = valid ? ns : 0;
            edst[idx] = valid ? nd : 0;
            ew[idx]   = valid ? w : 0.f;
            if (valid) atomicAdd(&shist[nd - b * k], 1);
        }
        __syncthreads();                      // shist final; ss/si free for reuse
        int* sscan = (int*)ss;                // scan scratch
        int* scur  = si;                      // per-node cursors
        int per2 = (k + 1023) >> 10;          // =2 for k<=1600
        int t0 = tid * per2, t1 = t0 + per2;
        if (t1 > k) t1 = k; if (t0 > k) t0 = k;
        int sloc = 0;
        for (int i = t0; i < t1; ++i) sloc += shist[i];
        sscan[tid] = sloc;
        __syncthreads();
        for (int d = 1; d < 1024; d <<= 1) {
            int t = sscan[tid] + ((tid >= d) ? sscan[tid - d] : 0);
            __syncthreads();
            sscan[tid] = t;
            __syncthreads();
        }
        int run = b * EPG + sscan[tid] - sloc;
        for (int i = t0; i < t1; ++i) {
            offs[b * k + i] = run; scur[i] = run;
            cntN[b * k + i] = shist[i];
            run += shist[i];
        }
        __syncthreads();
        for (int e = tid; e < EPG; e += 1024) {
            int idx = e0 + e;
            float w = ew[idx];
            if (w > 0.f) {
                int ns = esrc[idx], nd = edst[idx];
                int pos = atomicAdd(&scur[nd - b * k], 1);
                csr_src[pos] = ns;
                csr_norm[pos] = rsqrtf((float)(shist[ns - b * k] + 1)) *
                                rsqrtf((float)(shist[nd - b * k] + 1));
            }
        }
    }
}

// ---------------- standalone pool partials (layer 2 only) ----------------
__global__ __launch_bounds__(128) void k_pool_readout(const _Float16* __restrict__ X,
                                                      const float* __restrict__ gate,
                                                      const int* __restrict__ perm,
                                                      float* __restrict__ pmax,
                                                      float* __restrict__ psum, int k) {
    int s = blockIdx.x, b = blockIdx.y, f = threadIdx.x;
    int j0 = (k * s) / RSEG, j1 = (k * (s + 1)) / RSEG;
    float mx = -__builtin_inff(), sm = 0.f;
    for (int j = j0; j < j1; ++j) {
        int g = b * k + j;
        int old = perm[g];
        float v = (float)X[(size_t)old * NHID + f] * gate[g];
        mx = fmaxf(mx, v);
        sm += v;
    }
    pmax[(size_t)(b * RSEG + s) * NHID + f] = mx;
    psum[(size_t)(b * RSEG + s) * NHID + f] = sm;
}

// ---------------- fused layer-3 readout-combine + final linear ----------------
__global__ __launch_bounds__(128) void k_comb_final(const float* __restrict__ pmax,
                                                    const float* __restrict__ psum,
                                                    const float* __restrict__ accum,
                                                    const float* __restrict__ Wl,
                                                    const float* __restrict__ bl,
                                                    float* __restrict__ out, int k) {
    __shared__ float a[256];
    int b = blockIdx.x, f = threadIdx.x;
    float mx = -__builtin_inff(), sm = 0.f;
#pragma unroll
    for (int s = 0; s < RSEG; ++s) {
        mx = fmaxf(mx, pmax[(size_t)(b * RSEG + s) * NHID + f]);
        sm += psum[(size_t)(b * RSEG + s) * NHID + f];
    }
    a[f]       = accum[b * 256 + f] + mx;
    a[128 + f] = accum[b * 256 + 128 + f] + sm / (float)k;
    __syncthreads();
    float s = bl[f];
    for (int i = 0; i < 256; ++i) s = fmaf(a[i], Wl[i * NHID + f], s);
    out[b * NHID + f] = fmaxf(s, 0.f);
}

extern "C" void kernel_launch(void* const* d_in, const int* in_sizes, int n_in,
                              void* d_out, int out_size, void* d_ws, size_t ws_size,
                              hipStream_t stream) {
    const float* x0 = (const float*)d_in[0];
    const float* Wm[3] = {(const float*)d_in[1], (const float*)d_in[5], (const float*)d_in[9]};
    const float* bm[3] = {(const float*)d_in[2], (const float*)d_in[6], (const float*)d_in[10]};
    const float* Wsc[3] = {(const float*)d_in[3], (const float*)d_in[7], (const float*)d_in[11]};
    const float* bsc[3] = {(const float*)d_in[4], (const float*)d_in[8], (const float*)d_in[12]};
    const float* Wl = (const float*)d_in[13];
    const float* bl = (const float*)d_in[14];
    const int*   ei = (const int*)d_in[15];
    float* out = (float*)d_out;

    _Float16* bufA = (_Float16*)d_ws;                       // N0*128 halves (H)
    _Float16* bufB = bufA + (size_t)N0 * NHID;              // N0*128 (X)
    _Float16* WT1  = bufB + (size_t)N0 * NHID;              // 128*256
    _Float16* WT2  = WT1 + 128 * 256;                       // 128*128
    _Float16* WT3  = WT2 + 128 * 128;                       // 128*128
    float* hs     = (float*)(WT3 + 128 * 128);              // N0
    float* gate   = hs + N0;                                // N0
    float* accum  = gate + N0;                              // B*256
    float* pmax   = accum + B_GRAPHS * 256;                 // B*RSEG*128
    float* psum   = pmax + B_GRAPHS * RSEG * NHID;          // B*RSEG*128
    int*   cntA   = (int*)(psum + B_GRAPHS * RSEG * NHID);  // N0
    int*   cntB   = cntA + N0;                              // N0
    int*   offs   = cntB + N0;                              // N0
    int*   perm   = offs + N0;                              // N0
    int*   esrc   = perm + N0;                              // NE
    int*   edst   = esrc + NE;                              // NE
    float* ew     = (float*)(edst + NE);                    // NE
    int*   csr_src= (int*)(ew + NE);                        // NE
    float* csr_norm = (float*)(csr_src + NE);               // NE

    _Float16* WTs[3] = {WT1, WT2, WT3};
    const int EG = cdiv(NE, 256);

    k_fill_start<<<cdiv(N0, 256), 256, 0, stream>>>(cntA, accum);
    k_init_cvt<<<EG, 256, 0, stream>>>(ei, esrc, edst, ew, cntA,
                                       Wm[0], Wm[1], Wm[2], WT1, WT2, WT3);

    int npg = NPG0;
    _Float16* Hbuf = bufA; _Float16* Xbuf = bufB;

    for (int layer = 0; layer < 3; ++layer) {
        int N = B_GRAPHS * npg;
        int k = (npg * 4) / 5;   // ceil(0.8*n) exact for 2000/1600/1280
        int bpg = npg >> 2;      // blocks per graph in k_agg
        int* cnt  = (layer == 1) ? cntB : cntA;
        int* cntN = (layer == 1) ? cntA : cntB;
        int nseg = npg >> 6;     // pool segments from prev GEMM = rows/graph / 64

        if (layer == 0) {
            k_gemm_ws<1, 256, 0, 0><<<cdiv(N, 64), 256, 0, stream>>>(
                x0, WTs[0], perm, gate, Hbuf, N, pmax, psum);
            // layer-0 CSR comes from init edges; later layers build CSR inside scoretopk
            k_scancsr<<<B_GRAPHS, 1024, 0, stream>>>(cnt, offs, esrc, edst, ew,
                                                     csr_src, csr_norm, npg);
        } else {
            // gather GEMM also emits PREVIOUS layer's pool partials from resident rows
            k_gemm_ws<0, 128, 1, 1><<<cdiv(N, 64), 256, 0, stream>>>(
                Xbuf, WTs[layer], perm, gate, Hbuf, N, pmax, psum);
        }
        k_agg<<<8 * GSLOTS * bpg, 256, 0, stream>>>(Hbuf, csr_src, csr_norm, offs, cnt,
                                                    bm[layer], Wsc[layer], Xbuf, hs, bpg, npg);
        if (layer == 0)
            k_scoretopk<1, 0><<<B_GRAPHS, 1024, 0, stream>>>(hs, csr_src, csr_norm, offs, cnt,
                                                             bsc[layer], perm, gate,
                                                             esrc, edst, ew, cntN,
                                                             pmax, psum, accum, npg, k, 0);
        else if (layer == 1)
            k_scoretopk<1, 1><<<B_GRAPHS, 1024, 0, stream>>>(hs, csr_src, csr_norm, offs, cnt,
                                                             bsc[layer], perm, gate,
                                                             esrc, edst, ew, cntN,
                                                             pmax, psum, accum, npg, k, nseg);
        else
            k_scoretopk<0, 1><<<B_GRAPHS, 1024, 0, stream>>>(hs, csr_src, csr_norm, offs, cnt,
                                                             bsc[layer], perm, gate,
                                                             esrc, edst, ew, cntN,
                                                             pmax, psum, accum, npg, k, nseg);
        if (layer == 2) {
            k_pool_readout<<<dim3(RSEG, B_GRAPHS), 128, 0, stream>>>(Xbuf, gate, perm,
                                                                     pmax, psum, k);
            k_comb_final<<<B_GRAPHS, 128, 0, stream>>>(pmax, psum, accum, Wl, bl, out, k);
        }

        npg = k;
    }
}

// Round 15
// 532.304 us; speedup vs baseline: 1.0941x; 1.0129x over previous
//
#include <hip/hip_runtime.h>
#include <math.h>

#define B_GRAPHS 50
#define NPG0     2000
#define EPG      12000
#define F_IN_C   256
#define NHID     128
#define N0       (B_GRAPHS * NPG0)   // 100000
#define NE       (B_GRAPHS * EPG)    // 600000
#define RSEG     32                  // readout segments per graph (layer-2 standalone pool)
#define GSLOTS   7                   // ceil(50 graphs / 8 XCDs)
#define CPAD     136
#define KMAX     1600                // max next-layer nodes per graph (layer-0 k)

typedef _Float16 f16x8 __attribute__((ext_vector_type(8)));
typedef float    f32x4 __attribute__((ext_vector_type(4)));

static inline int cdiv(int a, int b) { return (a + b - 1) / b; }

// ===== fused startup: per-graph edge init + LDS degree hist + scan + CSR fill =====
// Blocks [0,50): graph b — read ei directly, write esrc/edst/ew, build scnt hist in
// LDS (no global cnt atomics, no pre-zero), write cnt, exclusive scan, fill CSR.
// Blocks [50,114): weight transposes (trivial role; host kernel is low-VGPR, so no
// round-7 allocator-compromise risk).
__global__ __launch_bounds__(1024) void k_csr_init(const int* __restrict__ ei,
                                                   int* __restrict__ esrc,
                                                   int* __restrict__ edst,
                                                   float* __restrict__ ew,
                                                   int* __restrict__ cnt,
                                                   int* __restrict__ offs,
                                                   int* __restrict__ csr_src,
                                                   float* __restrict__ csr_norm,
                                                   const float* __restrict__ W1,
                                                   const float* __restrict__ W2,
                                                   const float* __restrict__ W3,
                                                   _Float16* __restrict__ WT1,
                                                   _Float16* __restrict__ WT2,
                                                   _Float16* __restrict__ WT3,
                                                   int npg) {
    __shared__ int ch[1024];
    __shared__ int scnt[2048];
    __shared__ int scur[2048];
    int bid = blockIdx.x, tid = threadIdx.x;
    if (bid >= B_GRAPHS) {
        int t = (bid - B_GRAPHS) * 1024 + tid;        // [0, 65536)
        if (t < 128 * 256) {
            int n = t >> 8, kk = t & 255;
            WT1[t] = (_Float16)W1[kk * 128 + n];
        } else if (t < 128 * 256 + 128 * 128) {
            int u = t - 32768; int n = u >> 7, kk = u & 127;
            WT2[u] = (_Float16)W2[kk * 128 + n];
        } else if (t < 128 * 256 + 2 * 128 * 128) {
            int u = t - 49152; int n = u >> 7, kk = u & 127;
            WT3[u] = (_Float16)W3[kk * 128 + n];
        }
        return;
    }
    int b = bid, base = b * npg, e0 = b * EPG;
    for (int i = tid; i < npg; i += 1024) scnt[i] = 0;
    __syncthreads();
    // pass 1: edge init + LDS degree histogram
    for (int e = tid; e < EPG; e += 1024) {
        int s = ei[e0 + e], d = ei[NE + e0 + e];
        esrc[e0 + e] = s; edst[e0 + e] = d; ew[e0 + e] = 1.0f;
        atomicAdd(&scnt[d - base], 1);
    }
    __syncthreads();
    // exclusive scan over scnt -> offs/cursors; write cnt
    int per = (npg + 1023) >> 10;                     // =2 for npg<=2000
    int s0 = tid * per;
    int s1 = s0 + per; if (s1 > npg) s1 = npg; if (s0 > npg) s0 = npg;
    int s = 0;
    for (int i = s0; i < s1; ++i) s += scnt[i];
    ch[tid] = s;
    __syncthreads();
    for (int d = 1; d < 1024; d <<= 1) {
        int t = ch[tid] + ((tid >= d) ? ch[tid - d] : 0);
        __syncthreads();
        ch[tid] = t;
        __syncthreads();
    }
    int run = e0 + ch[tid] - s;
    for (int i = s0; i < s1; ++i) {
        cnt[base + i] = scnt[i];
        offs[base + i] = run; scur[i] = run;
        run += scnt[i];
    }
    __syncthreads();
    // fill pass (all L0 edges valid; esrc/edst L2-hot from pass 1)
    for (int e = tid; e < EPG; e += 1024) {
        int sN = esrc[e0 + e], d = edst[e0 + e];
        int pos = atomicAdd(&scur[d - base], 1);
        csr_src[pos] = sN;
        csr_norm[pos] = rsqrtf((float)(scnt[sN - base] + 1)) *
                        rsqrtf((float)(scnt[d - base] + 1));
    }
}

// ---------------- weight-stationary MFMA GEMM, 64-row M-tile (STANDALONE) ----------------
// Round-7 lesson: separate-role fat blocks force allocator compromise -> spills. POOL here
// is NOT a separate role: it reuses the gather rows already in this wave's registers (q0)
// to emit the PREVIOUS layer's readout partials (per-block, no atomics; blocks never
// straddle graphs since k % 64 == 0). Eliminates standalone k_pool_readout for L0/L1.
template<int FP32IN, int F, int GATHER, int POOL>
__global__ __launch_bounds__(256) void k_gemm_ws(const void* __restrict__ Xin,
                                                 const _Float16* __restrict__ WT,
                                                 const int* __restrict__ perm,
                                                 const float* __restrict__ gate,
                                                 _Float16* __restrict__ H, int N,
                                                 float* __restrict__ pmax,
                                                 float* __restrict__ psum) {
    constexpr int KH  = (F > 128) ? 128 : F;      // K-cols staged per phase (=128)
    constexpr int K8H = KH / 8;                   // f16x8 chunks per row per phase
    constexpr int SMEMSZ = (128 * KH > 64 * CPAD) ? 128 * KH : 64 * CPAD;
    __shared__ _Float16 smem[SMEMSZ];
    const int tid  = threadIdx.x;
    const int wave = tid >> 6, lane = tid & 63;
    const int quad = lane >> 4, l16 = lane & 15;
    const int m_blk = blockIdx.x * 64;

    f32x4 acc[8];
#pragma unroll
    for (int j = 0; j < 8; ++j) acc[j] = {0.f, 0.f, 0.f, 0.f};

    int row0 = m_blk + wave * 16 + l16;
    if (row0 > N - 1) row0 = N - 1;
    _Float16 g0 = (_Float16)1.0f;
    float g0f = 1.0f;
    if (GATHER) {
        g0f = gate[row0];
        g0 = (_Float16)g0f;
        row0 = perm[row0];
    }
    const int sx = l16 & 7;
    constexpr int NKQ = F / 32;

    f16x8 q0[NKQ];                                // F=128 row cache (reused by POOL)

    if (FP32IN) {
        constexpr int PD = (NKQ < 4) ? NKQ : 4;
        const float* base0 = (const float*)Xin + (size_t)row0 * F + quad * 8;
        float4 p0[PD][2];
        // A prologue first: HBM loads in flight while we stage W phase 0.
#pragma unroll
        for (int i = 0; i < PD; ++i) {
            p0[i][0] = ((const float4*)(base0 + i * 32))[0];
            p0[i][1] = ((const float4*)(base0 + i * 32))[1];
        }
        // stage W^T phase 0: columns k in [0, KH)
#pragma unroll
        for (int c = tid; c < 128 * K8H; c += 256) {
            int n = c / K8H, k8 = c - n * K8H;
            f16x8 v = *(const f16x8*)&WT[(size_t)(n * (F / 8) + k8) * 8];
            *(f16x8*)&smem[n * KH + ((k8 ^ (n & 7)) << 3)] = v;
        }
        __syncthreads();
#pragma unroll
        for (int kq = 0; kq < NKQ; ++kq) {
            if (KH < F && kq == NKQ / 2) {
                // phase flip: all waves done reading phase 0 -> restage phase 1
                __syncthreads();
#pragma unroll
                for (int c = tid; c < 128 * K8H; c += 256) {
                    int n = c / K8H, k8 = c - n * K8H;
                    f16x8 v = *(const f16x8*)&WT[(size_t)(n * (F / 8) + K8H + k8) * 8];
                    *(f16x8*)&smem[n * KH + ((k8 ^ (n & 7)) << 3)] = v;
                }
                __syncthreads();
            }
            const int b = kq % PD;
            float4 f0 = p0[b][0], f1 = p0[b][1];
            if (kq + PD < NKQ) {
                p0[b][0] = ((const float4*)(base0 + (kq + PD) * 32))[0];
                p0[b][1] = ((const float4*)(base0 + (kq + PD) * 32))[1];
            }
            f16x8 af0 = (f16x8){(_Float16)f0.x,(_Float16)f0.y,(_Float16)f0.z,(_Float16)f0.w,
                                (_Float16)f1.x,(_Float16)f1.y,(_Float16)f1.z,(_Float16)f1.w};
            f16x8 bf[8];
#pragma unroll
            for (int j = 0; j < 8; ++j)
                bf[j] = *(const f16x8*)&smem[(j * 16 + l16) * KH + (((((kq & 3) << 2) + quad) ^ sx) << 3)];
#pragma unroll
            for (int j = 0; j < 8; ++j)
                acc[j] = __builtin_amdgcn_mfma_f32_16x16x32_f16(af0, bf[j], acc[j], 0, 0, 0);
        }
    } else {
        // F=128: single stage, full prefetch — all NKQ loads issued before any MFMA
#pragma unroll
        for (int c = tid; c < 128 * K8H; c += 256) {
            int n = c / K8H, k8 = c - n * K8H;
            f16x8 v = *(const f16x8*)&WT[(size_t)(n * K8H + k8) * 8];
            *(f16x8*)&smem[n * KH + ((k8 ^ (n & 7)) << 3)] = v;
        }
        const _Float16* base0 = (const _Float16*)Xin + (size_t)row0 * F + quad * 8;
#pragma unroll
        for (int i = 0; i < NKQ; ++i)
            q0[i] = *(const f16x8*)(base0 + i * 32);
        __syncthreads();
#pragma unroll
        for (int kq = 0; kq < NKQ; ++kq) {
            f16x8 af0 = q0[kq];
            if (GATHER) af0 = af0 * g0;
            f16x8 bf[8];
#pragma unroll
            for (int j = 0; j < 8; ++j)
                bf[j] = *(const f16x8*)&smem[(j * 16 + l16) * KH + (((((kq & 3) << 2) + quad) ^ sx) << 3)];
#pragma unroll
            for (int j = 0; j < 8; ++j)
                acc[j] = __builtin_amdgcn_mfma_f32_16x16x32_f16(af0, bf[j], acc[j], 0, 0, 0);
        }
    }
    __syncthreads();   // done reading W; reuse LDS for epilogue

    _Float16* sC = smem;                  // [64][CPAD]
    const int rw = wave * 16;
#pragma unroll
    for (int j = 0; j < 8; ++j)
#pragma unroll
        for (int g = 0; g < 4; ++g)
            sC[(rw + quad * 4 + g) * CPAD + j * 16 + l16] = (_Float16)acc[j][g];
    __syncthreads();
    {
        int rr = tid >> 2;                // 0..63
        int cc = (tid & 3) * 32;          // 0,32,64,96 halves
        int gr = m_blk + rr;
        if (gr < N) {
            _Float16* Hr = H + (size_t)gr * 128 + cc;
            const _Float16* Sr = sC + rr * CPAD + cc;
#pragma unroll
            for (int c = 0; c < 4; ++c)
                *(f16x8*)&Hr[c * 8] = *(const f16x8*)&Sr[c * 8];
        }
    }
    if (POOL && GATHER && !FP32IN) {
        // ---- previous layer's readout partials from resident gather rows ----
        __syncthreads();                  // sC reads done; reuse smem
        float* smax = (float*)smem;       // [4][128]
        float* ssum = smax + 4 * 128;     // [4][128]
#pragma unroll
        for (int kq = 0; kq < NKQ; ++kq) {
#pragma unroll
            for (int j = 0; j < 8; ++j) {
                float v = (float)q0[kq][j] * g0f;
                float mx = v, sm = v;
#pragma unroll
                for (int s2 = 1; s2 < 16; s2 <<= 1) {
                    mx = fmaxf(mx, __shfl_xor(mx, s2, 64));
                    sm += __shfl_xor(sm, s2, 64);
                }
                if (l16 == 0) {
                    int f = kq * 32 + quad * 8 + j;
                    smax[wave * 128 + f] = mx;
                    ssum[wave * 128 + f] = sm;
                }
            }
        }
        __syncthreads();
        if (tid < 128) {
            float mx = fmaxf(fmaxf(smax[tid], smax[128 + tid]),
                             fmaxf(smax[256 + tid], smax[384 + tid]));
            float sm = ssum[tid] + ssum[128 + tid] + ssum[256 + tid] + ssum[384 + tid];
            int kprev = N / B_GRAPHS;     // rows per graph (divisible by 64)
            int g = m_blk / kprev;
            int blkg = (m_blk - g * kprev) >> 6;
            pmax[(size_t)(g * RSEG + blkg) * NHID + tid] = mx;
            psum[(size_t)(g * RSEG + blkg) * NHID + tid] = sm;
        }
    }
}

// -------- aggregation + fused score projection, 8-edge pipeline + XCD swizzle --------
__global__ __launch_bounds__(256) void k_agg(const _Float16* __restrict__ H,
                                             const int* __restrict__ csr_src,
                                             const float* __restrict__ csr_norm,
                                             const int* __restrict__ offs,
                                             const int* __restrict__ cnt,
                                             const float* __restrict__ bias,
                                             const float* __restrict__ Ws,
                                             _Float16* __restrict__ X,
                                             float* __restrict__ hs,
                                             int bpg, int npg) {
    int bi = blockIdx.x;
    int x = bi & 7, s = bi >> 3;
    int gslot = s / bpg, blk = s - gslot * bpg;
    int g = x + 8 * gslot;
    if (g >= B_GRAPHS) return;
    int node = g * npg + blk * 4 + (threadIdx.x >> 6);
    int lane = threadIdx.x & 63;
    int quad = lane >> 4, l16 = lane & 15;

    int st = offs[node], c = cnt[node], en = st + c;
    float acc[8];
#pragma unroll
    for (int j = 0; j < 8; ++j) acc[j] = 0.f;

    if (c > 0) {
        for (int e0 = st; e0 < en; e0 += 8) {
            int eA = e0 + quad, eB = eA + 4;
            int ecA = eA < en ? eA : en - 1;
            int ecB = eB < en ? eB : en - 1;
            int uA = csr_src[ecA], uB = csr_src[ecB];
            float nA = (eA < en) ? csr_norm[ecA] : 0.f;
            float nB = (eB < en) ? csr_norm[ecB] : 0.f;
            f16x8 hA = *(const f16x8*)&H[(size_t)uA * NHID + l16 * 8];
            f16x8 hB = *(const f16x8*)&H[(size_t)uB * NHID + l16 * 8];
#pragma unroll
            for (int j = 0; j < 8; ++j) acc[j] = fmaf((float)hA[j], nA, acc[j]);
#pragma unroll
            for (int j = 0; j < 8; ++j) acc[j] = fmaf((float)hB[j], nB, acc[j]);
        }
    }
#pragma unroll
    for (int j = 0; j < 8; ++j) {
        acc[j] += __shfl_xor(acc[j], 16, 64);
        acc[j] += __shfl_xor(acc[j], 32, 64);
    }
    float invd = 1.f / (float)(c + 1);
    f16x8 hn = *(const f16x8*)&H[(size_t)node * NHID + l16 * 8];
    float4 b0 = *(const float4*)&bias[l16 * 8];
    float4 b1 = *(const float4*)&bias[l16 * 8 + 4];
    float4 w0 = *(const float4*)&Ws[l16 * 8];
    float4 w1 = *(const float4*)&Ws[l16 * 8 + 4];
    const float bb[8] = {b0.x, b0.y, b0.z, b0.w, b1.x, b1.y, b1.z, b1.w};
    const float ww[8] = {w0.x, w0.y, w0.z, w0.w, w1.x, w1.y, w1.z, w1.w};
    float sd = 0.f;
    f16x8 o;
#pragma unroll
    for (int j = 0; j < 8; ++j) {
        float v = fmaxf(acc[j] + (float)hn[j] * invd + bb[j], 0.f);
        o[j] = (_Float16)v;
        sd = fmaf(v, ww[j], sd);
    }
    if (quad == 0)
        *(f16x8*)&X[(size_t)node * NHID + l16 * 8] = o;
    sd += __shfl_xor(sd, 1, 64);
    sd += __shfl_xor(sd, 2, 64);
    sd += __shfl_xor(sd, 4, 64);
    sd += __shfl_xor(sd, 8, 64);
    if (lane == 0) hs[node] = sd;
}

// --- fused: [COMB: fold prev-layer pool partials; 1=add 2=store] + score
//     + top-k (wave-resident bitonic) + remap + [REMAP: next-layer CSR build] ---
template<int REMAP, int COMB>
__global__ __launch_bounds__(1024) void k_scoretopk(const float* __restrict__ hs,
                                                    int* __restrict__ csr_src,
                                                    float* __restrict__ csr_norm,
                                                    int* __restrict__ offs,
                                                    const int* __restrict__ cnt,
                                                    const float* __restrict__ bs,
                                                    int* __restrict__ perm,
                                                    float* __restrict__ gate,
                                                    int* __restrict__ esrc,
                                                    int* __restrict__ edst,
                                                    float* __restrict__ ew,
                                                    int* __restrict__ cntN,
                                                    const float* __restrict__ pmax,
                                                    const float* __restrict__ psum,
                                                    float* __restrict__ accum,
                                                    int npg, int k, int nseg) {
    __shared__ float ss[2048];
    __shared__ int   si[2048];
    __shared__ float shs[2048];               // hs cache; reused as smap (int) later
    __shared__ int   shist[KMAX];
    int b = blockIdx.x, tid = threadIdx.x;
    int base = b * npg;

    if (COMB) {
        // fold previous layer's pool partials into accum (block b owns graph b).
        // COMB==2: first write (accum not zero-initialized anywhere).
        if (tid < 2 * NHID) {
            int f = tid & 127;
            bool isSum = tid >= NHID;
            float a2 = isSum ? 0.f : -__builtin_inff();
            for (int s = 0; s < nseg; ++s) {
                float v = (isSum ? psum : pmax)[(size_t)(b * RSEG + s) * NHID + f];
                a2 = isSum ? (a2 + v) : fmaxf(a2, v);
            }
            float val = isSum ? (a2 / (float)npg) : a2;
            int idx = b * 256 + (isSum ? 128 + f : f);
            if (COMB == 2) accum[idx] = val;
            else           accum[idx] += val;
        }
    }

    float bs0 = bs[0];
    for (int i = tid; i < 2048; i += 1024)
        shs[i] = (i < npg) ? hs[base + i] : 0.f;
    __syncthreads();
    for (int i = tid; i < 2048; i += 1024) {
        if (i < npg) {
            int st = offs[base + i], c = cnt[base + i];
            float a = 0.f;
            for (int e = st; e < st + c; ++e)
                a = fmaf(shs[csr_src[e] - base], csr_norm[e], a);
            ss[i] = a + shs[i] / (float)(c + 1) + bs0;
        } else {
            ss[i] = -__builtin_inff();
        }
        si[i] = i;
    }
    __syncthreads();

    // ---------------- wave-resident bitonic sort (desc score, asc idx) ----------------
    const int wbase = (tid >> 6) << 7;        // wave's 128-element base
    const int l = tid & 63;
    float vL = ss[wbase + l],      vH = ss[wbase + 64 + l];
    int   iL = si[wbase + l],      iH = si[wbase + 64 + l];

    auto reg_steps = [&](int size, int smax) {
        for (int s = smax; s > 0; s >>= 1) {
            if (s == 64) {
                bool fwd = (((wbase + l) & size) == 0);
                bool bba = (vH > vL) || (vH == vL && iH < iL);
                if (fwd ? bba : !bba) {
                    float tv = vL; vL = vH; vH = tv;
                    int ti = iL; iL = iH; iH = ti;
                }
            } else {
                bool iR = ((l & s) == 0);
                float pv = __shfl_xor(vL, s, 64);
                int   pi = __shfl_xor(iL, s, 64);
                float sa = iR ? vL : pv, sb = iR ? pv : vL;
                int   ia = iR ? iL : pi, ib = iR ? pi : iL;
                bool bba = (sb > sa) || (sb == sa && ib < ia);
                bool fwd = (((wbase + l) & size) == 0);
                if (fwd ? bba : !bba) { vL = pv; iL = pi; }
                pv = __shfl_xor(vH, s, 64);
                pi = __shfl_xor(iH, s, 64);
                sa = iR ? vH : pv; sb = iR ? pv : vH;
                ia = iR ? iH : pi; ib = iR ? pi : iH;
                bba = (sb > sa) || (sb == sa && ib < ia);
                bool fwd2 = (((wbase + 64 + l) & size) == 0);
                if (fwd2 ? bba : !bba) { vH = pv; iH = pi; }
            }
        }
    };

    for (int size = 2; size <= 128; size <<= 1)
        reg_steps(size, size >> 1);
    for (int size = 256; size <= 2048; size <<= 1) {
        ss[wbase + l] = vL;      si[wbase + l] = iL;
        ss[wbase + 64 + l] = vH; si[wbase + 64 + l] = iH;
        __syncthreads();
        for (int stride = size >> 1; stride >= 128; stride >>= 1) {
            int i = ((tid & ~(stride - 1)) << 1) | (tid & (stride - 1));
            int j = i | stride;
            float sa = ss[i], sb = ss[j];
            int   ia = si[i], ib = si[j];
            bool bba = (sb > sa) || (sb == sa && ib < ia);
            bool fwd = ((i & size) == 0);
            if (fwd ? bba : !bba) { ss[i] = sb; ss[j] = sa; si[i] = ib; si[j] = ia; }
            __syncthreads();
        }
        vL = ss[wbase + l];      iL = si[wbase + l];
        vH = ss[wbase + 64 + l]; iH = si[wbase + 64 + l];
        reg_steps(size, 64);
    }
    ss[wbase + l] = vL;      si[wbase + l] = iL;
    ss[wbase + 64 + l] = vH; si[wbase + 64 + l] = iH;
    __syncthreads();

    int* smap = (int*)shs;                    // safe: shs dead after score phase
    for (int j = tid; j < npg; j += 1024) {
        int ol = si[j];
        if (j < k) {
            int newg = b * k + j;
            perm[newg] = base + ol;
            smap[ol] = newg;
            gate[newg] = tanhf(ss[j]);
        } else {
            smap[ol] = -1;
        }
    }
    if (REMAP) {
        for (int j = tid; j < k; j += 1024) shist[j] = 0;
        __syncthreads();                      // also fences output-phase ss/si reads
        int e0 = b * EPG;
        for (int e = tid; e < EPG; e += 1024) {
            int idx = e0 + e;
            float w = ew[idx];
            bool valid = false;
            int ns = 0, nd = 0;
            if (w > 0.f) {                    // guard BEFORE map lookup
                ns = smap[esrc[idx] - base];
                nd = smap[edst[idx] - base];
                valid = (ns >= 0) && (nd >= 0);
            }
            esrc[idx] = valid ? ns : 0;
            edst[idx] = valid ? nd : 0;
            ew[idx]   = valid ? w : 0.f;
            if (valid) atomicAdd(&shist[nd - b * k], 1);
        }
        __syncthreads();                      // shist final; ss/si free for reuse
        int* sscan = (int*)ss;                // scan scratch
        int* scur  = si;                      // per-node cursors
        int per2 = (k + 1023) >> 10;          // =2 for k<=1600
        int t0 = tid * per2, t1 = t0 + per2;
        if (t1 > k) t1 = k; if (t0 > k) t0 = k;
        int sloc = 0;
        for (int i = t0; i < t1; ++i) sloc += shist[i];
        sscan[tid] = sloc;
        __syncthreads();
        for (int d = 1; d < 1024; d <<= 1) {
            int t = sscan[tid] + ((tid >= d) ? sscan[tid - d] : 0);
            __syncthreads();
            sscan[tid] = t;
            __syncthreads();
        }
        int run = b * EPG + sscan[tid] - sloc;
        for (int i = t0; i < t1; ++i) {
            offs[b * k + i] = run; scur[i] = run;
            cntN[b * k + i] = shist[i];
            run += shist[i];
        }
        __syncthreads();
        for (int e = tid; e < EPG; e += 1024) {
            int idx = e0 + e;
            float w = ew[idx];
            if (w > 0.f) {
                int ns = esrc[idx], nd = edst[idx];
                int pos = atomicAdd(&scur[nd - b * k], 1);
                csr_src[pos] = ns;
                csr_norm[pos] = rsqrtf((float)(shist[ns - b * k] + 1)) *
                                rsqrtf((float)(shist[nd - b * k] + 1));
            }
        }
    }
}

// ---------------- standalone pool partials (layer 2 only) ----------------
__global__ __launch_bounds__(128) void k_pool_readout(const _Float16* __restrict__ X,
                                                      const float* __restrict__ gate,
                                                      const int* __restrict__ perm,
                                                      float* __restrict__ pmax,
                                                      float* __restrict__ psum, int k) {
    int s = blockIdx.x, b = blockIdx.y, f = threadIdx.x;
    int j0 = (k * s) / RSEG, j1 = (k * (s + 1)) / RSEG;
    float mx = -__builtin_inff(), sm = 0.f;
    for (int j = j0; j < j1; ++j) {
        int g = b * k + j;
        int old = perm[g];
        float v = (float)X[(size_t)old * NHID + f] * gate[g];
        mx = fmaxf(mx, v);
        sm += v;
    }
    pmax[(size_t)(b * RSEG + s) * NHID + f] = mx;
    psum[(size_t)(b * RSEG + s) * NHID + f] = sm;
}

// ---------------- fused layer-3 readout-combine + final linear ----------------
__global__ __launch_bounds__(128) void k_comb_final(const float* __restrict__ pmax,
                                                    const float* __restrict__ psum,
                                                    const float* __restrict__ accum,
                                                    const float* __restrict__ Wl,
                                                    const float* __restrict__ bl,
                                                    float* __restrict__ out, int k) {
    __shared__ float a[256];
    int b = blockIdx.x, f = threadIdx.x;
    float mx = -__builtin_inff(), sm = 0.f;
#pragma unroll
    for (int s = 0; s < RSEG; ++s) {
        mx = fmaxf(mx, pmax[(size_t)(b * RSEG + s) * NHID + f]);
        sm += psum[(size_t)(b * RSEG + s) * NHID + f];
    }
    a[f]       = accum[b * 256 + f] + mx;
    a[128 + f] = accum[b * 256 + 128 + f] + sm / (float)k;
    __syncthreads();
    float s = bl[f];
    for (int i = 0; i < 256; ++i) s = fmaf(a[i], Wl[i * NHID + f], s);
    out[b * NHID + f] = fmaxf(s, 0.f);
}

extern "C" void kernel_launch(void* const* d_in, const int* in_sizes, int n_in,
                              void* d_out, int out_size, void* d_ws, size_t ws_size,
                              hipStream_t stream) {
    const float* x0 = (const float*)d_in[0];
    const float* Wm[3] = {(const float*)d_in[1], (const float*)d_in[5], (const float*)d_in[9]};
    const float* bm[3] = {(const float*)d_in[2], (const float*)d_in[6], (const float*)d_in[10]};
    const float* Wsc[3] = {(const float*)d_in[3], (const float*)d_in[7], (const float*)d_in[11]};
    const float* bsc[3] = {(const float*)d_in[4], (const float*)d_in[8], (const float*)d_in[12]};
    const float* Wl = (const float*)d_in[13];
    const float* bl = (const float*)d_in[14];
    const int*   ei = (const int*)d_in[15];
    float* out = (float*)d_out;

    _Float16* bufA = (_Float16*)d_ws;                       // N0*128 halves (H)
    _Float16* bufB = bufA + (size_t)N0 * NHID;              // N0*128 (X)
    _Float16* WT1  = bufB + (size_t)N0 * NHID;              // 128*256
    _Float16* WT2  = WT1 + 128 * 256;                       // 128*128
    _Float16* WT3  = WT2 + 128 * 128;                       // 128*128
    float* hs     = (float*)(WT3 + 128 * 128);              // N0
    float* gate   = hs + N0;                                // N0
    float* accum  = gate + N0;                              // B*256
    float* pmax   = accum + B_GRAPHS * 256;                 // B*RSEG*128
    float* psum   = pmax + B_GRAPHS * RSEG * NHID;          // B*RSEG*128
    int*   cntA   = (int*)(psum + B_GRAPHS * RSEG * NHID);  // N0
    int*   cntB   = cntA + N0;                              // N0
    int*   offs   = cntB + N0;                              // N0
    int*   perm   = offs + N0;                              // N0
    int*   esrc   = perm + N0;                              // NE
    int*   edst   = esrc + NE;                              // NE
    float* ew     = (float*)(edst + NE);                    // NE
    int*   csr_src= (int*)(ew + NE);                        // NE
    float* csr_norm = (float*)(csr_src + NE);               // NE

    _Float16* WTs[3] = {WT1, WT2, WT3};

    int npg = NPG0;
    _Float16* Hbuf = bufA; _Float16* Xbuf = bufB;

    // fused startup: edge init + L0 CSR build (50 blocks) + weight cvt (64 blocks)
    k_csr_init<<<B_GRAPHS + 64, 1024, 0, stream>>>(ei, esrc, edst, ew, cntA, offs,
                                                   csr_src, csr_norm,
                                                   Wm[0], Wm[1], Wm[2],
                                                   WT1, WT2, WT3, npg);

    for (int layer = 0; layer < 3; ++layer) {
        int N = B_GRAPHS * npg;
        int k = (npg * 4) / 5;   // ceil(0.8*n) exact for 2000/1600/1280
        int bpg = npg >> 2;      // blocks per graph in k_agg
        int* cnt  = (layer == 1) ? cntB : cntA;
        int* cntN = (layer == 1) ? cntA : cntB;
        int nseg = npg >> 6;     // pool segments from prev GEMM = rows/graph / 64

        if (layer == 0) {
            k_gemm_ws<1, 256, 0, 0><<<cdiv(N, 64), 256, 0, stream>>>(
                x0, WTs[0], perm, gate, Hbuf, N, pmax, psum);
        } else {
            // gather GEMM also emits PREVIOUS layer's pool partials from resident rows
            k_gemm_ws<0, 128, 1, 1><<<cdiv(N, 64), 256, 0, stream>>>(
                Xbuf, WTs[layer], perm, gate, Hbuf, N, pmax, psum);
        }
        k_agg<<<8 * GSLOTS * bpg, 256, 0, stream>>>(Hbuf, csr_src, csr_norm, offs, cnt,
                                                    bm[layer], Wsc[layer], Xbuf, hs, bpg, npg);
        if (layer == 0)
            k_scoretopk<1, 0><<<B_GRAPHS, 1024, 0, stream>>>(hs, csr_src, csr_norm, offs, cnt,
                                                             bsc[layer], perm, gate,
                                                             esrc, edst, ew, cntN,
                                                             pmax, psum, accum, npg, k, 0);
        else if (layer == 1)
            k_scoretopk<1, 2><<<B_GRAPHS, 1024, 0, stream>>>(hs, csr_src, csr_norm, offs, cnt,
                                                             bsc[layer], perm, gate,
                                                             esrc, edst, ew, cntN,
                                                             pmax, psum, accum, npg, k, nseg);
        else
            k_scoretopk<0, 1><<<B_GRAPHS, 1024, 0, stream>>>(hs, csr_src, csr_norm, offs, cnt,
                                                             bsc[layer], perm, gate,
                                                             esrc, edst, ew, cntN,
                                                             pmax, psum, accum, npg, k, nseg);
        if (layer == 2) {
            k_pool_readout<<<dim3(RSEG, B_GRAPHS), 128, 0, stream>>>(Xbuf, gate, perm,
                                                                     pmax, psum, k);
            k_comb_final<<<B_GRAPHS, 128, 0, stream>>>(pmax, psum, accum, Wl, bl, out, k);
        }

        npg = k;
    }
}